// Round 1
// baseline (2317.042 us; speedup 1.0000x reference)
//
#include <hip/hip_runtime.h>
#include <hip/hip_bf16.h>

#define HIDC 2048
#define NHEADS 16
#define HDIM 128
#define NB 4
#define NS 4096
#define NROWS (NB*NS)
#define EPSV 1e-6f

typedef __attribute__((ext_vector_type(8))) short s16x8;
typedef __attribute__((ext_vector_type(4))) float f32x4;
typedef __attribute__((ext_vector_type(8))) unsigned short u16x8;

static __device__ __forceinline__ unsigned short f2b(float f) {
  unsigned int u = __float_as_uint(f);
  u += 0x7fffu + ((u >> 16) & 1u);
  return (unsigned short)(u >> 16);
}
static __device__ __forceinline__ float b2f(unsigned short h) {
  return __uint_as_float(((unsigned int)h) << 16);
}

// C[M,N] = act(A[M,K] @ B[N,K]^T + bias[N])
// A: fp32 or bf16 (template), B: fp32 always, out: bf16 or fp32.
template<int A_BF16, int ACT_ELU, int OUT_BF16>
__global__ __launch_bounds__(256) void gemm_bt(
    const void* __restrict__ Ap, const float* __restrict__ Bp,
    const float* __restrict__ bias, void* __restrict__ Cp,
    int Mdim, int Ndim, int Kdim)
{
  __shared__ unsigned short As[128][72];   // 64 bf16 + 8 pad, row stride 144B
  __shared__ unsigned short Bs[128][72];
  const int tid  = threadIdx.x;
  const int lane = tid & 63;
  const int wid  = tid >> 6;
  const int wr = wid >> 1, wc = wid & 1;
  const int l15 = lane & 15, l4 = lane >> 4;
  const int ntile = Ndim >> 7;
  const int bm = (int)(blockIdx.x / ntile) << 7;
  const int bn = (int)(blockIdx.x % ntile) << 7;

  f32x4 acc[4][4] = {};

  for (int kt = 0; kt < Kdim; kt += 64) {
    __syncthreads();
    if (A_BF16) {
      const unsigned short* A16 = (const unsigned short*)Ap;
      #pragma unroll
      for (int i = 0; i < 4; ++i) {
        int idx = tid + (i << 8);          // 0..1023, 8x16B per row
        int row = idx >> 3, q = idx & 7;
        u16x8 v8 = *(const u16x8*)(A16 + (size_t)(bm + row) * Kdim + kt + (q << 3));
        *(u16x8*)&As[row][q << 3] = v8;
      }
    } else {
      const float* Af = (const float*)Ap;
      #pragma unroll
      for (int i = 0; i < 8; ++i) {
        int idx = tid + (i << 8);          // 0..2047, 16 float4 per row
        int row = idx >> 4, q = idx & 15;
        float4 v4 = *(const float4*)(Af + (size_t)(bm + row) * Kdim + kt + (q << 2));
        ushort4 w4; w4.x = f2b(v4.x); w4.y = f2b(v4.y); w4.z = f2b(v4.z); w4.w = f2b(v4.w);
        *(ushort4*)&As[row][q << 2] = w4;
      }
    }
    {
      #pragma unroll
      for (int i = 0; i < 8; ++i) {
        int idx = tid + (i << 8);
        int row = idx >> 4, q = idx & 15;
        float4 v4 = *(const float4*)(Bp + (size_t)(bn + row) * Kdim + kt + (q << 2));
        ushort4 w4; w4.x = f2b(v4.x); w4.y = f2b(v4.y); w4.z = f2b(v4.z); w4.w = f2b(v4.w);
        *(ushort4*)&Bs[row][q << 2] = w4;
      }
    }
    __syncthreads();
    #pragma unroll
    for (int kk = 0; kk < 64; kk += 32) {
      s16x8 af[4], bfr[4];
      #pragma unroll
      for (int mf = 0; mf < 4; ++mf)
        af[mf] = *(const s16x8*)&As[(wr << 6) + (mf << 4) + l15][kk + (l4 << 3)];
      #pragma unroll
      for (int nf = 0; nf < 4; ++nf)
        bfr[nf] = *(const s16x8*)&Bs[(wc << 6) + (nf << 4) + l15][kk + (l4 << 3)];
      #pragma unroll
      for (int mf = 0; mf < 4; ++mf)
        #pragma unroll
        for (int nf = 0; nf < 4; ++nf)
          acc[mf][nf] = __builtin_amdgcn_mfma_f32_16x16x32_bf16(af[mf], bfr[nf], acc[mf][nf], 0, 0, 0);
    }
  }

  #pragma unroll
  for (int nf = 0; nf < 4; ++nf) {
    const int col = bn + (wc << 6) + (nf << 4) + l15;
    const float bv = bias[col];
    #pragma unroll
    for (int mf = 0; mf < 4; ++mf) {
      #pragma unroll
      for (int r = 0; r < 4; ++r) {
        const int row = bm + (wr << 6) + (mf << 4) + (l4 << 2) + r;
        float v = acc[mf][nf][r] + bv;
        if (ACT_ELU) v = (v > 0.f) ? (v + 1.f) : __expf(v);
        if (OUT_BF16) ((unsigned short*)Cp)[(size_t)row * Ndim + col] = f2b(v);
        else          ((float*)Cp)[(size_t)row * Ndim + col] = v;
      }
    }
  }
}

// kv partials: block = (bh, s-chunk). acc[d8][e8] per thread (8x8), deterministic
// partial outputs kvp[(chunk*64+bh)][e][d] (transposed!), ksp[(chunk*64+bh)][d].
__global__ __launch_bounds__(256) void kv_partial(
    const unsigned short* __restrict__ kp, const unsigned short* __restrict__ vv,
    float* __restrict__ kvp, float* __restrict__ ksp)
{
  const int bh = blockIdx.x >> 3;
  const int chunk = blockIdx.x & 7;
  const int b = bh >> 4, h = bh & 15;
  const int tid = threadIdx.x;
  const int td = tid >> 4, te = tid & 15;

  __shared__ float kpl[32][128];
  __shared__ float vl[32][132];

  float acc[8][8] = {};
  float ks[8] = {};

  const size_t rowbase = (size_t)b * NS * HIDC + (size_t)h * HDIM;
  const int s0 = chunk * 512;

  for (int st = 0; st < 512; st += 32) {
    __syncthreads();
    #pragma unroll
    for (int i = 0; i < 2; ++i) {
      int idx = tid + (i << 8);          // 0..511
      int row = idx >> 4, q = idx & 15;  // 16 groups of 8 per 128-row
      size_t g = rowbase + (size_t)(s0 + st + row) * HIDC + (q << 3);
      u16x8 k8 = *(const u16x8*)(kp + g);
      u16x8 v8 = *(const u16x8*)(vv + g);
      float tk[8], tv[8];
      #pragma unroll
      for (int j = 0; j < 8; ++j) { tk[j] = b2f(k8[j]); tv[j] = b2f(v8[j]); }
      *(float4*)&kpl[row][(q << 3)]     = make_float4(tk[0], tk[1], tk[2], tk[3]);
      *(float4*)&kpl[row][(q << 3) + 4] = make_float4(tk[4], tk[5], tk[6], tk[7]);
      *(float4*)&vl[row][(q << 3)]      = make_float4(tv[0], tv[1], tv[2], tv[3]);
      *(float4*)&vl[row][(q << 3) + 4]  = make_float4(tv[4], tv[5], tv[6], tv[7]);
    }
    __syncthreads();
    #pragma unroll 4
    for (int s = 0; s < 32; ++s) {
      float kd[8], ve[8];
      *(float4*)&kd[0] = *(const float4*)&kpl[s][td << 3];
      *(float4*)&kd[4] = *(const float4*)&kpl[s][(td << 3) + 4];
      *(float4*)&ve[0] = *(const float4*)&vl[s][te << 3];
      *(float4*)&ve[4] = *(const float4*)&vl[s][(te << 3) + 4];
      if (te == 0) {
        #pragma unroll
        for (int i = 0; i < 8; ++i) ks[i] += kd[i];
      }
      #pragma unroll
      for (int i = 0; i < 8; ++i)
        #pragma unroll
        for (int j = 0; j < 8; ++j)
          acc[i][j] += kd[i] * ve[j];
    }
  }

  float* outp = kvp + ((size_t)(chunk * 64 + bh) << 14);
  #pragma unroll
  for (int j = 0; j < 8; ++j) {
    int e = (te << 3) + j;
    float r0[8];
    #pragma unroll
    for (int i = 0; i < 8; ++i) r0[i] = acc[i][j];
    *(float4*)&outp[(size_t)e * HDIM + (td << 3)]     = *(float4*)&r0[0];
    *(float4*)&outp[(size_t)e * HDIM + (td << 3) + 4] = *(float4*)&r0[4];
  }
  if (te == 0) {
    float* kso = ksp + ((size_t)(chunk * 64 + bh) << 7) + (td << 3);
    #pragma unroll
    for (int i = 0; i < 8; ++i) kso[i] = ks[i];
  }
}

__global__ __launch_bounds__(256) void kv_reduce(
    const float* __restrict__ kvp, float* __restrict__ kvT)
{
  int i = blockIdx.x * 256 + threadIdx.x;   // < 64*16384
  float s = 0.f;
  #pragma unroll
  for (int c = 0; c < 8; ++c) s += kvp[(size_t)c * (64 * 16384) + i];
  kvT[i] = s;
}

// attn[s,e] = (qp[s,:] . kvT[e,:]) / (z[s]+eps), block = (bh, 128-row s-tile)
__global__ __launch_bounds__(256) void attn_ker(
    const unsigned short* __restrict__ qp, const float* __restrict__ kvT,
    const float* __restrict__ ksp, unsigned short* __restrict__ attn)
{
  const int bh = blockIdx.x >> 5, stile = blockIdx.x & 31;
  const int b = bh >> 4, h = bh & 15;
  const int tid = threadIdx.x;
  const int lane = tid & 63, w = tid >> 6;
  const int l15 = lane & 15, l4 = lane >> 4;

  __shared__ unsigned short Qs[128][136];
  __shared__ unsigned short Ks[128][136];
  __shared__ float ksl[128];
  __shared__ float zs[128];

  const size_t qbase = ((size_t)b * NS + (size_t)stile * 128) * HIDC + (size_t)h * HDIM;

  #pragma unroll
  for (int i = 0; i < 8; ++i) {
    int idx = tid + (i << 8);           // 0..2047
    int row = idx >> 4, q = idx & 15;
    u16x8 v8 = *(const u16x8*)(qp + qbase + (size_t)row * HIDC + (q << 3));
    *(u16x8*)&Qs[row][q << 3] = v8;
  }
  const float* kvb = kvT + ((size_t)bh << 14);
  #pragma unroll
  for (int i = 0; i < 16; ++i) {
    int idx = tid + (i << 8);           // 0..4095
    int row = idx >> 5, q = idx & 31;
    float4 v4 = *(const float4*)(kvb + (size_t)row * HDIM + (q << 2));
    ushort4 w4; w4.x = f2b(v4.x); w4.y = f2b(v4.y); w4.z = f2b(v4.z); w4.w = f2b(v4.w);
    *(ushort4*)&Ks[row][q << 2] = w4;
  }
  if (tid < 128) {
    float s = 0.f;
    #pragma unroll
    for (int c = 0; c < 8; ++c) s += ksp[((size_t)(c * 64 + bh) << 7) + tid];
    ksl[tid] = s;
  }
  __syncthreads();
  if (tid < 128) {
    float z = 0.f;
    #pragma unroll
    for (int dq = 0; dq < 16; ++dq) {
      u16x8 qv = *(const u16x8*)&Qs[tid][dq << 3];
      #pragma unroll
      for (int j = 0; j < 8; ++j) z += b2f(qv[j]) * ksl[(dq << 3) + j];
    }
    zs[tid] = 1.f / (z + EPSV);
  }
  __syncthreads();

  f32x4 acc[2][8] = {};
  #pragma unroll
  for (int kk = 0; kk < 4; ++kk) {
    s16x8 a[2], bb[8];
    #pragma unroll
    for (int mf = 0; mf < 2; ++mf)
      a[mf] = *(const s16x8*)&Qs[(w << 5) + (mf << 4) + l15][(kk << 5) + (l4 << 3)];
    #pragma unroll
    for (int nf = 0; nf < 8; ++nf)
      bb[nf] = *(const s16x8*)&Ks[(nf << 4) + l15][(kk << 5) + (l4 << 3)];
    #pragma unroll
    for (int mf = 0; mf < 2; ++mf)
      #pragma unroll
      for (int nf = 0; nf < 8; ++nf)
        acc[mf][nf] = __builtin_amdgcn_mfma_f32_16x16x32_bf16(a[mf], bb[nf], acc[mf][nf], 0, 0, 0);
  }

  #pragma unroll
  for (int mf = 0; mf < 2; ++mf) {
    #pragma unroll
    for (int r = 0; r < 4; ++r) {
      const int rl = (w << 5) + (mf << 4) + (l4 << 2) + r;
      const float zi = zs[rl];
      #pragma unroll
      for (int nf = 0; nf < 8; ++nf) {
        const int e = (nf << 4) + l15;
        attn[qbase + (size_t)rl * HIDC + e] = f2b(acc[mf][nf][r] * zi);
      }
    }
  }
}

extern "C" void kernel_launch(void* const* d_in, const int* in_sizes, int n_in,
                              void* d_out, int out_size, void* d_ws, size_t ws_size,
                              hipStream_t stream) {
  const float* hs = (const float*)d_in[0];
  const float* qw = (const float*)d_in[1];
  const float* qb = (const float*)d_in[2];
  const float* kw = (const float*)d_in[3];
  const float* kb = (const float*)d_in[4];
  const float* vw = (const float*)d_in[5];
  const float* vb = (const float*)d_in[6];
  const float* ow = (const float*)d_in[7];
  const float* ob = (const float*)d_in[8];

  char* w = (char*)d_ws;
  unsigned short* qp = (unsigned short*)(w);                     // 64 MB bf16
  unsigned short* kp = (unsigned short*)(w + 67108864);          // 64 MB
  unsigned short* vp = (unsigned short*)(w + 134217728);         // 64 MB
  unsigned short* at = (unsigned short*)(w + 201326592);         // 64 MB
  float* kvp = (float*)(w + 268435456);                          // 32 MB partials
  float* ksp = (float*)(w + 268435456 + 33554432);               // 256 KB
  float* kvT = (float*)(w + 268435456 + 33554432 + 262144);      // 4 MB

  dim3 blk(256);
  gemm_bt<0, 1, 1><<<dim3(2048), blk, 0, stream>>>(hs, qw, qb, qp, NROWS, HIDC, HIDC);
  gemm_bt<0, 1, 1><<<dim3(2048), blk, 0, stream>>>(hs, kw, kb, kp, NROWS, HIDC, HIDC);
  gemm_bt<0, 0, 1><<<dim3(2048), blk, 0, stream>>>(hs, vw, vb, vp, NROWS, HIDC, HIDC);
  kv_partial<<<dim3(512), blk, 0, stream>>>(kp, vp, kvp, ksp);
  kv_reduce<<<dim3(4096), blk, 0, stream>>>(kvp, kvT);
  attn_ker<<<dim3(2048), blk, 0, stream>>>(qp, kvT, ksp, at);
  gemm_bt<1, 0, 0><<<dim3(2048), blk, 0, stream>>>(at, ow, ob, d_out, NROWS, HIDC, HIDC);
}

// Round 2
// 1068.182 us; speedup vs baseline: 2.1691x; 2.1691x over previous
//
#include <hip/hip_runtime.h>
#include <hip/hip_bf16.h>

#define HIDC 2048
#define NHEADS 16
#define HDIM 128
#define NB 4
#define NS 4096
#define NROWS (NB*NS)
#define QSTR 6144
#define EPSV 1e-6f

typedef __attribute__((ext_vector_type(8))) short s16x8;
typedef __attribute__((ext_vector_type(4))) float f32x4;
typedef __attribute__((ext_vector_type(8))) unsigned short u16x8;

static __device__ __forceinline__ unsigned short f2b(float f) {
  unsigned int u = __float_as_uint(f);
  u += 0x7fffu + ((u >> 16) & 1u);
  return (unsigned short)(u >> 16);
}
static __device__ __forceinline__ float b2f(unsigned short h) {
  return __uint_as_float(((unsigned int)h) << 16);
}

static __device__ __forceinline__ void gload_lds16(const unsigned short* g, unsigned short* l) {
  __builtin_amdgcn_global_load_lds(
      (const __attribute__((address_space(1))) void*)g,
      (__attribute__((address_space(3))) void*)l, 16, 0, 0);
}

// fp32 -> bf16 conversion for hs (16384 blocks) + 4 weights (2048 blocks each)
__global__ __launch_bounds__(256) void convert_all(
    const float* __restrict__ hs, const float* __restrict__ qw,
    const float* __restrict__ kw, const float* __restrict__ vw,
    const float* __restrict__ ow,
    unsigned short* __restrict__ hsb, unsigned short* __restrict__ qwb,
    unsigned short* __restrict__ kwb, unsigned short* __restrict__ vwb,
    unsigned short* __restrict__ owb)
{
  int bid = blockIdx.x;
  const float* src; unsigned short* dst; size_t base;
  if (bid < 16384) { src = hs; dst = hsb; base = (size_t)bid << 11; }
  else {
    int t = bid - 16384; int wsel = t >> 11; int wb = t & 2047;
    src = wsel == 0 ? qw : wsel == 1 ? kw : wsel == 2 ? vw : ow;
    dst = wsel == 0 ? qwb : wsel == 1 ? kwb : wsel == 2 ? vwb : owb;
    base = (size_t)wb << 11;
  }
  size_t i = base + ((size_t)threadIdx.x << 3);
  float4 a = *(const float4*)(src + i);
  float4 b = *(const float4*)(src + i + 4);
  u16x8 o;
  o[0] = f2b(a.x); o[1] = f2b(a.y); o[2] = f2b(a.z); o[3] = f2b(a.w);
  o[4] = f2b(b.x); o[5] = f2b(b.y); o[6] = f2b(b.z); o[7] = f2b(b.w);
  *(u16x8*)(dst + i) = o;
}

// m97-structure bf16 GEMM: C[M,N] = act(A @ B^T + bias), 128x128 tile, BK=64,
// global_load_lds width-16 staging, linear LDS, 4 waves x (4x4) 16x16x32 MFMA.
// QKV=1: N=6144 split into 3 weight segments (seg uniform per block), elu on seg<2.
template<int QKV, int OUT_BF16>
__global__ __launch_bounds__(256) void gemm16(
    const unsigned short* __restrict__ A,
    const unsigned short* __restrict__ B0,
    const unsigned short* __restrict__ B1,
    const unsigned short* __restrict__ B2,
    const float* __restrict__ bias0,
    const float* __restrict__ bias1,
    const float* __restrict__ bias2,
    void* __restrict__ Cp,
    int Kdim, int ntile, int astr, int ostr)
{
  __shared__ unsigned short As[128 * 64];
  __shared__ unsigned short Bs[128 * 64];
  const int tid = threadIdx.x;
  const int lane = tid & 63, wid = tid >> 6;
  const int wr = wid >> 1, wc = wid & 1;
  const int l15 = lane & 15, l4 = lane >> 4;
  const int bm = (int)(blockIdx.x / ntile) << 7;
  const int bn = (int)(blockIdx.x % ntile) << 7;

  const unsigned short* Bp = B0;
  const float* bias = bias0;
  bool act = false;
  int bnw = bn;
  if (QKV) {
    int seg = bn >> 11;
    Bp = seg == 0 ? B0 : (seg == 1 ? B1 : B2);
    bias = seg == 0 ? bias0 : (seg == 1 ? bias1 : bias2);
    act = seg < 2;
    bnw = bn & 2047;
  }

  const int lrow = lane >> 3;          // 0..7
  const int lcol = (lane & 7) << 3;    // 0..56 step 8

  f32x4 acc[4][4] = {};

  for (int kt = 0; kt < Kdim; kt += 64) {
    __syncthreads();
    #pragma unroll
    for (int i = 0; i < 4; ++i) {
      const int chunk = (i << 2) + wid;                   // 0..15, uniform per wave
      const unsigned short* ga = A + (size_t)(bm + (chunk << 3) + lrow) * astr + kt + lcol;
      gload_lds16(ga, &As[chunk << 9]);
      const unsigned short* gb = Bp + (size_t)(bnw + (chunk << 3) + lrow) * Kdim + kt + lcol;
      gload_lds16(gb, &Bs[chunk << 9]);
    }
    __syncthreads();
    #pragma unroll
    for (int kk = 0; kk < 64; kk += 32) {
      s16x8 af[4], bf[4];
      #pragma unroll
      for (int mf = 0; mf < 4; ++mf)
        af[mf] = *(const s16x8*)&As[(((wr << 6) + (mf << 4) + l15) << 6) + kk + (l4 << 3)];
      #pragma unroll
      for (int nf = 0; nf < 4; ++nf)
        bf[nf] = *(const s16x8*)&Bs[(((wc << 6) + (nf << 4) + l15) << 6) + kk + (l4 << 3)];
      #pragma unroll
      for (int mf = 0; mf < 4; ++mf)
        #pragma unroll
        for (int nf = 0; nf < 4; ++nf)
          acc[mf][nf] = __builtin_amdgcn_mfma_f32_16x16x32_bf16(af[mf], bf[nf], acc[mf][nf], 0, 0, 0);
    }
  }

  #pragma unroll
  for (int nf = 0; nf < 4; ++nf) {
    const int colw = (wc << 6) + (nf << 4) + l15;
    const float bv = bias[bnw + colw];
    #pragma unroll
    for (int mf = 0; mf < 4; ++mf) {
      #pragma unroll
      for (int r = 0; r < 4; ++r) {
        const int row = bm + (wr << 6) + (mf << 4) + (l4 << 2) + r;
        float v = acc[mf][nf][r] + bv;
        if (QKV) { if (act) v = (v > 0.f) ? (v + 1.f) : __expf(v); }
        const size_t off = (size_t)row * ostr + bn + colw;
        if (OUT_BF16) ((unsigned short*)Cp)[off] = f2b(v);
        else          ((float*)Cp)[off] = v;
      }
    }
  }
}

// kv partials over 8 S-chunks (deterministic, no atomics).
// kp/vv point at the k/v column blocks of qkv (row stride QSTR).
__global__ __launch_bounds__(256) void kv_partial(
    const unsigned short* __restrict__ kp, const unsigned short* __restrict__ vv,
    float* __restrict__ kvp, float* __restrict__ ksp)
{
  const int bh = blockIdx.x >> 3;
  const int chunk = blockIdx.x & 7;
  const int b = bh >> 4, h = bh & 15;
  const int tid = threadIdx.x;
  const int td = tid >> 4, te = tid & 15;

  __shared__ float kpl[32][128];
  __shared__ float vl[32][132];

  float acc[8][8] = {};
  float ks[8] = {};

  const size_t rowbase = (size_t)b * NS * QSTR + (size_t)h * HDIM;
  const int s0 = chunk * 512;

  for (int st = 0; st < 512; st += 32) {
    __syncthreads();
    #pragma unroll
    for (int i = 0; i < 2; ++i) {
      int idx = tid + (i << 8);
      int row = idx >> 4, q = idx & 15;
      size_t g = rowbase + (size_t)(s0 + st + row) * QSTR + (q << 3);
      u16x8 k8 = *(const u16x8*)(kp + g);
      u16x8 v8 = *(const u16x8*)(vv + g);
      float tk[8], tv[8];
      #pragma unroll
      for (int j = 0; j < 8; ++j) { tk[j] = b2f(k8[j]); tv[j] = b2f(v8[j]); }
      *(float4*)&kpl[row][(q << 3)]     = make_float4(tk[0], tk[1], tk[2], tk[3]);
      *(float4*)&kpl[row][(q << 3) + 4] = make_float4(tk[4], tk[5], tk[6], tk[7]);
      *(float4*)&vl[row][(q << 3)]      = make_float4(tv[0], tv[1], tv[2], tv[3]);
      *(float4*)&vl[row][(q << 3) + 4]  = make_float4(tv[4], tv[5], tv[6], tv[7]);
    }
    __syncthreads();
    #pragma unroll 4
    for (int s = 0; s < 32; ++s) {
      float kd[8], ve[8];
      *(float4*)&kd[0] = *(const float4*)&kpl[s][td << 3];
      *(float4*)&kd[4] = *(const float4*)&kpl[s][(td << 3) + 4];
      *(float4*)&ve[0] = *(const float4*)&vl[s][te << 3];
      *(float4*)&ve[4] = *(const float4*)&vl[s][(te << 3) + 4];
      if (te == 0) {
        #pragma unroll
        for (int i = 0; i < 8; ++i) ks[i] += kd[i];
      }
      #pragma unroll
      for (int i = 0; i < 8; ++i)
        #pragma unroll
        for (int j = 0; j < 8; ++j)
          acc[i][j] += kd[i] * ve[j];
    }
  }

  float* outp = kvp + ((size_t)(chunk * 64 + bh) << 14);
  #pragma unroll
  for (int j = 0; j < 8; ++j) {
    int e = (te << 3) + j;
    float r0[8];
    #pragma unroll
    for (int i = 0; i < 8; ++i) r0[i] = acc[i][j];
    *(float4*)&outp[(size_t)e * HDIM + (td << 3)]     = *(float4*)&r0[0];
    *(float4*)&outp[(size_t)e * HDIM + (td << 3) + 4] = *(float4*)&r0[4];
  }
  if (te == 0) {
    float* kso = ksp + ((size_t)(chunk * 64 + bh) << 7) + (td << 3);
    #pragma unroll
    for (int i = 0; i < 8; ++i) kso[i] = ks[i];
  }
}

__global__ __launch_bounds__(256) void kv_reduce(
    const float* __restrict__ kvp, float* __restrict__ kvT)
{
  int i = blockIdx.x * 256 + threadIdx.x;
  float s = 0.f;
  #pragma unroll
  for (int c = 0; c < 8; ++c) s += kvp[(size_t)c * (64 * 16384) + i];
  kvT[i] = s;
}

// attn[s,e] = (qp[s,:] . kvT[e,:]) / (z[s]+eps); qp = q cols of qkv, out -> v cols.
__global__ __launch_bounds__(256) void attn_ker(
    const unsigned short* __restrict__ qp, const float* __restrict__ kvT,
    const float* __restrict__ ksp, unsigned short* __restrict__ attn)
{
  const int bh = blockIdx.x >> 5, stile = blockIdx.x & 31;
  const int b = bh >> 4, h = bh & 15;
  const int tid = threadIdx.x;
  const int lane = tid & 63, w = tid >> 6;
  const int l15 = lane & 15, l4 = lane >> 4;

  __shared__ unsigned short Qs[128][136];
  __shared__ unsigned short Ks[128][136];
  __shared__ float ksl[128];
  __shared__ float zs[128];

  const size_t qbase = ((size_t)b * NS + (size_t)stile * 128) * QSTR + (size_t)h * HDIM;

  #pragma unroll
  for (int i = 0; i < 8; ++i) {
    int idx = tid + (i << 8);
    int row = idx >> 4, q = idx & 15;
    u16x8 v8 = *(const u16x8*)(qp + qbase + (size_t)row * QSTR + (q << 3));
    *(u16x8*)&Qs[row][q << 3] = v8;
  }
  const float* kvb = kvT + ((size_t)bh << 14);
  #pragma unroll
  for (int i = 0; i < 16; ++i) {
    int idx = tid + (i << 8);
    int row = idx >> 5, q = idx & 31;
    float4 v4 = *(const float4*)(kvb + (size_t)row * HDIM + (q << 2));
    ushort4 w4; w4.x = f2b(v4.x); w4.y = f2b(v4.y); w4.z = f2b(v4.z); w4.w = f2b(v4.w);
    *(ushort4*)&Ks[row][q << 2] = w4;
  }
  if (tid < 128) {
    float s = 0.f;
    #pragma unroll
    for (int c = 0; c < 8; ++c) s += ksp[((size_t)(c * 64 + bh) << 7) + tid];
    ksl[tid] = s;
  }
  __syncthreads();
  if (tid < 128) {
    float z = 0.f;
    #pragma unroll
    for (int dq = 0; dq < 16; ++dq) {
      u16x8 qv = *(const u16x8*)&Qs[tid][dq << 3];
      #pragma unroll
      for (int j = 0; j < 8; ++j) z += b2f(qv[j]) * ksl[(dq << 3) + j];
    }
    zs[tid] = 1.f / (z + EPSV);
  }
  __syncthreads();

  f32x4 acc[2][8] = {};
  #pragma unroll
  for (int kk = 0; kk < 4; ++kk) {
    s16x8 a[2], bb[8];
    #pragma unroll
    for (int mf = 0; mf < 2; ++mf)
      a[mf] = *(const s16x8*)&Qs[(w << 5) + (mf << 4) + l15][(kk << 5) + (l4 << 3)];
    #pragma unroll
    for (int nf = 0; nf < 8; ++nf)
      bb[nf] = *(const s16x8*)&Ks[(nf << 4) + l15][(kk << 5) + (l4 << 3)];
    #pragma unroll
    for (int mf = 0; mf < 2; ++mf)
      #pragma unroll
      for (int nf = 0; nf < 8; ++nf)
        acc[mf][nf] = __builtin_amdgcn_mfma_f32_16x16x32_bf16(a[mf], bb[nf], acc[mf][nf], 0, 0, 0);
  }

  #pragma unroll
  for (int mf = 0; mf < 2; ++mf) {
    #pragma unroll
    for (int r = 0; r < 4; ++r) {
      const int rl = (w << 5) + (mf << 4) + (l4 << 2) + r;
      const float zi = zs[rl];
      #pragma unroll
      for (int nf = 0; nf < 8; ++nf) {
        const int e = (nf << 4) + l15;
        attn[qbase + (size_t)rl * QSTR + e] = f2b(acc[mf][nf][r] * zi);
      }
    }
  }
}

extern "C" void kernel_launch(void* const* d_in, const int* in_sizes, int n_in,
                              void* d_out, int out_size, void* d_ws, size_t ws_size,
                              hipStream_t stream) {
  const float* hs = (const float*)d_in[0];
  const float* qw = (const float*)d_in[1];
  const float* qb = (const float*)d_in[2];
  const float* kw = (const float*)d_in[3];
  const float* kb = (const float*)d_in[4];
  const float* vw = (const float*)d_in[5];
  const float* vb = (const float*)d_in[6];
  const float* ow = (const float*)d_in[7];
  const float* ob = (const float*)d_in[8];

  char* w = (char*)d_ws;
  unsigned short* hsb = (unsigned short*)(w);                  // 64 MiB (dead after QKV gemm)
  unsigned short* qwb = (unsigned short*)(w + 67108864);       // 8 MiB
  unsigned short* kwb = (unsigned short*)(w + 75497472);
  unsigned short* vwb = (unsigned short*)(w + 83886080);
  unsigned short* owb = (unsigned short*)(w + 92274688);
  unsigned short* qkv = (unsigned short*)(w + 100663296);      // 192 MiB, row stride 6144
  // aliases over the dead hsb region:
  float* kvp = (float*)(w);                                    // 32 MiB
  float* ksp = (float*)(w + 33554432);                         // 256 KiB
  float* kvT = (float*)(w + 33816576);                         // 4 MiB

  dim3 blk(256);
  convert_all<<<dim3(24576), blk, 0, stream>>>(hs, qw, kw, vw, ow, hsb, qwb, kwb, vwb, owb);
  // QKV fused: M=16384, N=6144 (q|k|v columns), elu+1 on q,k
  gemm16<1, 1><<<dim3(128 * 48), blk, 0, stream>>>(
      hsb, qwb, kwb, vwb, qb, kb, vb, qkv, HIDC, 48, HIDC, QSTR);
  kv_partial<<<dim3(512), blk, 0, stream>>>(qkv + 2048, qkv + 4096, kvp, ksp);
  kv_reduce<<<dim3(4096), blk, 0, stream>>>(kvp, kvT);
  attn_ker<<<dim3(2048), blk, 0, stream>>>(qkv, kvT, ksp, qkv + 4096);
  // final: out = attn @ o_w^T + o_b, A = v-columns of qkv (astr=QSTR), fp32 out
  gemm16<0, 0><<<dim3(128 * 16), blk, 0, stream>>>(
      qkv + 4096, owb, owb, owb, ob, ob, ob, d_out, HIDC, 16, QSTR, HIDC);
}

// Round 3
// 842.059 us; speedup vs baseline: 2.7516x; 1.2685x over previous
//
#include <hip/hip_runtime.h>
#include <hip/hip_bf16.h>

#define HIDC 2048
#define NHEADS 16
#define HDIM 128
#define NB 4
#define NS 4096
#define NROWS (NB*NS)
#define QSTR 6144
#define EPSV 1e-6f

typedef __attribute__((ext_vector_type(8))) short s16x8;
typedef __attribute__((ext_vector_type(4))) float f32x4;
typedef __attribute__((ext_vector_type(8))) unsigned short u16x8;

static __device__ __forceinline__ unsigned short f2b(float f) {
  unsigned int u = __float_as_uint(f);
  u += 0x7fffu + ((u >> 16) & 1u);
  return (unsigned short)(u >> 16);
}
static __device__ __forceinline__ float b2f(unsigned short h) {
  return __uint_as_float(((unsigned int)h) << 16);
}

static __device__ __forceinline__ void gload_lds16(const unsigned short* g, unsigned short* l) {
  __builtin_amdgcn_global_load_lds(
      (const __attribute__((address_space(1))) void*)g,
      (__attribute__((address_space(3))) void*)l, 16, 0, 0);
}

// fp32 -> bf16 conversion for hs (16384 blocks) + 4 weights (2048 blocks each)
__global__ __launch_bounds__(256) void convert_all(
    const float* __restrict__ hs, const float* __restrict__ qw,
    const float* __restrict__ kw, const float* __restrict__ vw,
    const float* __restrict__ ow,
    unsigned short* __restrict__ hsb, unsigned short* __restrict__ qwb,
    unsigned short* __restrict__ kwb, unsigned short* __restrict__ vwb,
    unsigned short* __restrict__ owb)
{
  int bid = blockIdx.x;
  const float* src; unsigned short* dst; size_t base;
  if (bid < 16384) { src = hs; dst = hsb; base = (size_t)bid << 11; }
  else {
    int t = bid - 16384; int wsel = t >> 11; int wb = t & 2047;
    src = wsel == 0 ? qw : wsel == 1 ? kw : wsel == 2 ? vw : ow;
    dst = wsel == 0 ? qwb : wsel == 1 ? kwb : wsel == 2 ? vwb : owb;
    base = (size_t)wb << 11;
  }
  size_t i = base + ((size_t)threadIdx.x << 3);
  float4 a = *(const float4*)(src + i);
  float4 b = *(const float4*)(src + i + 4);
  u16x8 o;
  o[0] = f2b(a.x); o[1] = f2b(a.y); o[2] = f2b(a.z); o[3] = f2b(a.w);
  o[4] = f2b(b.x); o[5] = f2b(b.y); o[6] = f2b(b.z); o[7] = f2b(b.w);
  *(u16x8*)(dst + i) = o;
}

// 256x256-tile bf16 GEMM, 8 waves (2Mx4N), BK=32, ring-of-4 LDS slots,
// 2 phases/K-step (16 MFMA each), counted vmcnt(4) gate, XOR-swizzled LDS,
// stages issued 2 K-steps ahead. K fixed = 2048 (64 steps).
// C[M,N] = act(A[M,K] @ B[N,K]^T + bias[N]).
template<int QKV, int OUT_BF16>
__global__ __launch_bounds__(512, 2) void gemm256(
    const unsigned short* __restrict__ A,
    const unsigned short* __restrict__ B0,
    const unsigned short* __restrict__ B1,
    const unsigned short* __restrict__ B2,
    const float* __restrict__ bias0,
    const float* __restrict__ bias1,
    const float* __restrict__ bias2,
    void* __restrict__ Cp,
    int mtile, int astr, int ostr)
{
  __shared__ unsigned short lds[65536];   // 128 KiB: [slot:4][op:2][8192]
  const int tid = threadIdx.x;
  const int lane = tid & 63, wid = tid >> 6;
  const int wr = wid >> 2, wc = wid & 3;
  const int l15 = lane & 15, l4 = lane >> 4;

  // bijective XCD swizzle (grid % 8 == 0), bn-outer / bm-inner
  const int cpx = (int)gridDim.x >> 3;
  const int bidx = (int)blockIdx.x;
  const int wg = (bidx & 7) * cpx + (bidx >> 3);
  const int bm = (wg % mtile) << 8;
  const int bn = (wg / mtile) << 8;

  const unsigned short* Bp = B0;
  const float* bias = bias0;
  bool act = false;
  int bnw = bn;
  if (QKV) {
    int seg = bn >> 11;
    Bp = seg == 0 ? B0 : (seg == 1 ? B1 : B2);
    bias = seg == 0 ? bias0 : (seg == 1 ? bias1 : bias2);
    act = seg < 2;
    bnw = bn & 2047;
  }

  // staging geometry: wave stages chunks {2*wid, 2*wid+1} of A and of B.
  // chunk c = rows c*16..c*16+15 x 32 cols (1024B). lane: row=c*16+(l>>2),
  // source col pre-swizzled so linear LDS + swizzled read = consistent.
  const int c0 = wid << 1;
  const int srow = lane >> 2;
  const int scol = (((lane & 3) ^ (srow & 3)) << 3);
  const unsigned short* Asrc0 = A + (size_t)(bm + (c0 << 4) + srow) * astr + scol;
  const unsigned short* Asrc1 = Asrc0 + (size_t)16 * astr;
  const unsigned short* Bsrc0 = Bp + (size_t)(bnw + (c0 << 4) + srow) * HIDC + scol;
  const unsigned short* Bsrc1 = Bsrc0 + (size_t)16 * HIDC;
  const int adst = c0 << 9;               // ushort idx within op region

  // fragment read offsets (swizzled): row*32 + ((l4 ^ (row&3))<<3)
  const int xa = ((l4 ^ (l15 & 3)) << 3);
  const int abase = ((wr << 7) + l15) * 32 + xa;
  const int bbase = 8192 + ((wc << 6) + l15) * 32 + xa;

  f32x4 acc[8][4] = {};

#define STAGE_A(s_) { const int sl_ = ((s_) & 3) << 14; const int kt_ = (s_) << 5; \
    gload_lds16(Asrc0 + kt_, &lds[sl_ + adst]); \
    gload_lds16(Asrc1 + kt_, &lds[sl_ + adst + 512]); }
#define STAGE_B(s_) { const int sl_ = ((s_) & 3) << 14; const int kt_ = (s_) << 5; \
    gload_lds16(Bsrc0 + kt_, &lds[sl_ + 8192 + adst]); \
    gload_lds16(Bsrc1 + kt_, &lds[sl_ + 8192 + adst + 512]); }

#define DO_STEP(s_, STG, GATE) { \
    const int sl = ((s_) & 3) << 14; \
    s16x8 a[8], bl[2], bh[2]; \
    _Pragma("unroll") for (int mf = 0; mf < 8; ++mf) \
      a[mf] = *(const s16x8*)&lds[sl + abase + (mf << 9)]; \
    bl[0] = *(const s16x8*)&lds[sl + bbase]; \
    bl[1] = *(const s16x8*)&lds[sl + bbase + 512]; \
    if (STG) STAGE_A((s_) + 2); \
    __builtin_amdgcn_s_barrier(); \
    __builtin_amdgcn_s_setprio(1); \
    _Pragma("unroll") for (int mf = 0; mf < 8; ++mf) { \
      acc[mf][0] = __builtin_amdgcn_mfma_f32_16x16x32_bf16(a[mf], bl[0], acc[mf][0], 0, 0, 0); \
      acc[mf][1] = __builtin_amdgcn_mfma_f32_16x16x32_bf16(a[mf], bl[1], acc[mf][1], 0, 0, 0); } \
    __builtin_amdgcn_s_setprio(0); \
    __builtin_amdgcn_s_barrier(); \
    bh[0] = *(const s16x8*)&lds[sl + bbase + 1024]; \
    bh[1] = *(const s16x8*)&lds[sl + bbase + 1536]; \
    if (STG) STAGE_B((s_) + 2); \
    __builtin_amdgcn_s_barrier(); \
    __builtin_amdgcn_s_setprio(1); \
    _Pragma("unroll") for (int mf = 0; mf < 8; ++mf) { \
      acc[mf][2] = __builtin_amdgcn_mfma_f32_16x16x32_bf16(a[mf], bh[0], acc[mf][2], 0, 0, 0); \
      acc[mf][3] = __builtin_amdgcn_mfma_f32_16x16x32_bf16(a[mf], bh[1], acc[mf][3], 0, 0, 0); } \
    __builtin_amdgcn_s_setprio(0); \
    if ((GATE) == 4) { asm volatile("s_waitcnt vmcnt(4)" ::: "memory"); } \
    else if ((GATE) == 0) { asm volatile("s_waitcnt vmcnt(0)" ::: "memory"); } \
    __builtin_amdgcn_s_barrier(); \
    __builtin_amdgcn_sched_barrier(0); \
  }

  // prologue: stage slots 0 and 1; gate on slot 0
  STAGE_A(0); STAGE_B(0);
  STAGE_A(1); STAGE_B(1);
  asm volatile("s_waitcnt vmcnt(4)" ::: "memory");
  __builtin_amdgcn_s_barrier();
  __builtin_amdgcn_sched_barrier(0);

  for (int s = 0; s < 62; ++s) DO_STEP(s, 1, 4);
  DO_STEP(62, 0, 0);
  DO_STEP(63, 0, -1);

#undef DO_STEP
#undef STAGE_A
#undef STAGE_B

  #pragma unroll
  for (int nf = 0; nf < 4; ++nf) {
    const int colw = (wc << 6) + (nf << 4) + l15;
    const float bv = bias[bnw + colw];
    #pragma unroll
    for (int mf = 0; mf < 8; ++mf) {
      #pragma unroll
      for (int r = 0; r < 4; ++r) {
        const int row = bm + (wr << 7) + (mf << 4) + (l4 << 2) + r;
        float v = acc[mf][nf][r] + bv;
        if (QKV) { if (act) v = (v > 0.f) ? (v + 1.f) : __expf(v); }
        const size_t off = (size_t)row * ostr + bn + colw;
        if (OUT_BF16) ((unsigned short*)Cp)[off] = f2b(v);
        else          ((float*)Cp)[off] = v;
      }
    }
  }
}

// kv partials over 8 S-chunks (deterministic, no atomics).
__global__ __launch_bounds__(256) void kv_partial(
    const unsigned short* __restrict__ kp, const unsigned short* __restrict__ vv,
    float* __restrict__ kvp, float* __restrict__ ksp)
{
  const int bh = blockIdx.x >> 3;
  const int chunk = blockIdx.x & 7;
  const int b = bh >> 4, h = bh & 15;
  const int tid = threadIdx.x;
  const int td = tid >> 4, te = tid & 15;

  __shared__ float kpl[32][128];
  __shared__ float vl[32][132];

  float acc[8][8] = {};
  float ks[8] = {};

  const size_t rowbase = (size_t)b * NS * QSTR + (size_t)h * HDIM;
  const int s0 = chunk * 512;

  for (int st = 0; st < 512; st += 32) {
    __syncthreads();
    #pragma unroll
    for (int i = 0; i < 2; ++i) {
      int idx = tid + (i << 8);
      int row = idx >> 4, q = idx & 15;
      size_t g = rowbase + (size_t)(s0 + st + row) * QSTR + (q << 3);
      u16x8 k8 = *(const u16x8*)(kp + g);
      u16x8 v8 = *(const u16x8*)(vv + g);
      float tk[8], tv[8];
      #pragma unroll
      for (int j = 0; j < 8; ++j) { tk[j] = b2f(k8[j]); tv[j] = b2f(v8[j]); }
      *(float4*)&kpl[row][(q << 3)]     = make_float4(tk[0], tk[1], tk[2], tk[3]);
      *(float4*)&kpl[row][(q << 3) + 4] = make_float4(tk[4], tk[5], tk[6], tk[7]);
      *(float4*)&vl[row][(q << 3)]      = make_float4(tv[0], tv[1], tv[2], tv[3]);
      *(float4*)&vl[row][(q << 3) + 4]  = make_float4(tv[4], tv[5], tv[6], tv[7]);
    }
    __syncthreads();
    #pragma unroll 4
    for (int s = 0; s < 32; ++s) {
      float kd[8], ve[8];
      *(float4*)&kd[0] = *(const float4*)&kpl[s][td << 3];
      *(float4*)&kd[4] = *(const float4*)&kpl[s][(td << 3) + 4];
      *(float4*)&ve[0] = *(const float4*)&vl[s][te << 3];
      *(float4*)&ve[4] = *(const float4*)&vl[s][(te << 3) + 4];
      if (te == 0) {
        #pragma unroll
        for (int i = 0; i < 8; ++i) ks[i] += kd[i];
      }
      #pragma unroll
      for (int i = 0; i < 8; ++i)
        #pragma unroll
        for (int j = 0; j < 8; ++j)
          acc[i][j] += kd[i] * ve[j];
    }
  }

  float* outp = kvp + ((size_t)(chunk * 64 + bh) << 14);
  #pragma unroll
  for (int j = 0; j < 8; ++j) {
    int e = (te << 3) + j;
    float r0[8];
    #pragma unroll
    for (int i = 0; i < 8; ++i) r0[i] = acc[i][j];
    *(float4*)&outp[(size_t)e * HDIM + (td << 3)]     = *(float4*)&r0[0];
    *(float4*)&outp[(size_t)e * HDIM + (td << 3) + 4] = *(float4*)&r0[4];
  }
  if (te == 0) {
    float* kso = ksp + ((size_t)(chunk * 64 + bh) << 7) + (td << 3);
    #pragma unroll
    for (int i = 0; i < 8; ++i) kso[i] = ks[i];
  }
}

__global__ __launch_bounds__(256) void kv_reduce(
    const float* __restrict__ kvp, float* __restrict__ kvT)
{
  int i = blockIdx.x * 256 + threadIdx.x;
  float s = 0.f;
  #pragma unroll
  for (int c = 0; c < 8; ++c) s += kvp[(size_t)c * (64 * 16384) + i];
  kvT[i] = s;
}

// attn[s,e] = (qp[s,:] . kvT[e,:]) / (z[s]+eps); qp = q cols of qkv, out -> v cols.
__global__ __launch_bounds__(256) void attn_ker(
    const unsigned short* __restrict__ qp, const float* __restrict__ kvT,
    const float* __restrict__ ksp, unsigned short* __restrict__ attn)
{
  const int bh = blockIdx.x >> 5, stile = blockIdx.x & 31;
  const int b = bh >> 4, h = bh & 15;
  const int tid = threadIdx.x;
  const int lane = tid & 63, w = tid >> 6;
  const int l15 = lane & 15, l4 = lane >> 4;

  __shared__ unsigned short Qs[128][136];
  __shared__ unsigned short Ks[128][136];
  __shared__ float ksl[128];
  __shared__ float zs[128];

  const size_t qbase = ((size_t)b * NS + (size_t)stile * 128) * QSTR + (size_t)h * HDIM;

  #pragma unroll
  for (int i = 0; i < 8; ++i) {
    int idx = tid + (i << 8);
    int row = idx >> 4, q = idx & 15;
    u16x8 v8 = *(const u16x8*)(qp + qbase + (size_t)row * QSTR + (q << 3));
    *(u16x8*)&Qs[row][q << 3] = v8;
  }
  const float* kvb = kvT + ((size_t)bh << 14);
  #pragma unroll
  for (int i = 0; i < 16; ++i) {
    int idx = tid + (i << 8);
    int row = idx >> 5, q = idx & 31;
    float4 v4 = *(const float4*)(kvb + (size_t)row * HDIM + (q << 2));
    ushort4 w4; w4.x = f2b(v4.x); w4.y = f2b(v4.y); w4.z = f2b(v4.z); w4.w = f2b(v4.w);
    *(ushort4*)&Ks[row][q << 2] = w4;
  }
  if (tid < 128) {
    float s = 0.f;
    #pragma unroll
    for (int c = 0; c < 8; ++c) s += ksp[((size_t)(c * 64 + bh) << 7) + tid];
    ksl[tid] = s;
  }
  __syncthreads();
  if (tid < 128) {
    float z = 0.f;
    #pragma unroll
    for (int dq = 0; dq < 16; ++dq) {
      u16x8 qv = *(const u16x8*)&Qs[tid][dq << 3];
      #pragma unroll
      for (int j = 0; j < 8; ++j) z += b2f(qv[j]) * ksl[(dq << 3) + j];
    }
    zs[tid] = 1.f / (z + EPSV);
  }
  __syncthreads();

  f32x4 acc[2][8] = {};
  #pragma unroll
  for (int kk = 0; kk < 4; ++kk) {
    s16x8 a[2], bb[8];
    #pragma unroll
    for (int mf = 0; mf < 2; ++mf)
      a[mf] = *(const s16x8*)&Qs[(w << 5) + (mf << 4) + l15][(kk << 5) + (l4 << 3)];
    #pragma unroll
    for (int nf = 0; nf < 8; ++nf)
      bb[nf] = *(const s16x8*)&Ks[(nf << 4) + l15][(kk << 5) + (l4 << 3)];
    #pragma unroll
    for (int mf = 0; mf < 2; ++mf)
      #pragma unroll
      for (int nf = 0; nf < 8; ++nf)
        acc[mf][nf] = __builtin_amdgcn_mfma_f32_16x16x32_bf16(a[mf], bb[nf], acc[mf][nf], 0, 0, 0);
  }

  #pragma unroll
  for (int mf = 0; mf < 2; ++mf) {
    #pragma unroll
    for (int r = 0; r < 4; ++r) {
      const int rl = (w << 5) + (mf << 4) + (l4 << 2) + r;
      const float zi = zs[rl];
      #pragma unroll
      for (int nf = 0; nf < 8; ++nf) {
        const int e = (nf << 4) + l15;
        attn[qbase + (size_t)rl * QSTR + e] = f2b(acc[mf][nf][r] * zi);
      }
    }
  }
}

extern "C" void kernel_launch(void* const* d_in, const int* in_sizes, int n_in,
                              void* d_out, int out_size, void* d_ws, size_t ws_size,
                              hipStream_t stream) {
  const float* hs = (const float*)d_in[0];
  const float* qw = (const float*)d_in[1];
  const float* qb = (const float*)d_in[2];
  const float* kw = (const float*)d_in[3];
  const float* kb = (const float*)d_in[4];
  const float* vw = (const float*)d_in[5];
  const float* vb = (const float*)d_in[6];
  const float* ow = (const float*)d_in[7];
  const float* ob = (const float*)d_in[8];

  char* w = (char*)d_ws;
  unsigned short* hsb = (unsigned short*)(w);                  // 64 MiB (dead after QKV gemm)
  unsigned short* qwb = (unsigned short*)(w + 67108864);       // 8 MiB each
  unsigned short* kwb = (unsigned short*)(w + 75497472);
  unsigned short* vwb = (unsigned short*)(w + 83886080);
  unsigned short* owb = (unsigned short*)(w + 92274688);
  unsigned short* qkv = (unsigned short*)(w + 100663296);      // 192 MiB, row stride 6144
  // aliases over the dead hsb region:
  float* kvp = (float*)(w);                                    // 32 MiB
  float* ksp = (float*)(w + 33554432);                         // 256 KiB
  float* kvT = (float*)(w + 33816576);                         // 4 MiB

  convert_all<<<dim3(24576), dim3(256), 0, stream>>>(hs, qw, kw, vw, ow, hsb, qwb, kwb, vwb, owb);
  // QKV fused: M=16384, N=6144 (q|k|v columns), elu+1 on q,k
  gemm256<1, 1><<<dim3(24 * 64), dim3(512), 0, stream>>>(
      hsb, qwb, kwb, vwb, qb, kb, vb, qkv, 64, HIDC, QSTR);
  kv_partial<<<dim3(512), dim3(256), 0, stream>>>(qkv + 2048, qkv + 4096, kvp, ksp);
  kv_reduce<<<dim3(4096), dim3(256), 0, stream>>>(kvp, kvT);
  attn_ker<<<dim3(2048), dim3(256), 0, stream>>>(qkv, kvT, ksp, qkv + 4096);
  // final: out = attn @ o_w^T + o_b, A = v-columns of qkv (astr=QSTR), fp32 out
  gemm256<0, 0><<<dim3(8 * 64), dim3(512), 0, stream>>>(
      qkv + 4096, owb, owb, owb, ob, ob, ob, d_out, 64, QSTR, HIDC);
}

// Round 4
// 830.688 us; speedup vs baseline: 2.7893x; 1.0137x over previous
//
#include <hip/hip_runtime.h>
#include <hip/hip_bf16.h>

#define HIDC 2048
#define NHEADS 16
#define HDIM 128
#define NB 4
#define NS 4096
#define NROWS (NB*NS)
#define QSTR 6144
#define EPSV 1e-6f

typedef __attribute__((ext_vector_type(8))) short s16x8;
typedef __attribute__((ext_vector_type(4))) float f32x4;
typedef __attribute__((ext_vector_type(8))) unsigned short u16x8;

static __device__ __forceinline__ unsigned short f2b(float f) {
  unsigned int u = __float_as_uint(f);
  u += 0x7fffu + ((u >> 16) & 1u);
  return (unsigned short)(u >> 16);
}
static __device__ __forceinline__ float b2f(unsigned short h) {
  return __uint_as_float(((unsigned int)h) << 16);
}

static __device__ __forceinline__ void gload_lds16(const unsigned short* g, unsigned short* l) {
  __builtin_amdgcn_global_load_lds(
      (const __attribute__((address_space(1))) void*)g,
      (__attribute__((address_space(3))) void*)l, 16, 0, 0);
}

// fp32 -> bf16 conversion for hs (16384 blocks) + 4 weights (2048 blocks each)
__global__ __launch_bounds__(256) void convert_all(
    const float* __restrict__ hs, const float* __restrict__ qw,
    const float* __restrict__ kw, const float* __restrict__ vw,
    const float* __restrict__ ow,
    unsigned short* __restrict__ hsb, unsigned short* __restrict__ qwb,
    unsigned short* __restrict__ kwb, unsigned short* __restrict__ vwb,
    unsigned short* __restrict__ owb)
{
  int bid = blockIdx.x;
  const float* src; unsigned short* dst; size_t base;
  if (bid < 16384) { src = hs; dst = hsb; base = (size_t)bid << 11; }
  else {
    int t = bid - 16384; int wsel = t >> 11; int wb = t & 2047;
    src = wsel == 0 ? qw : wsel == 1 ? kw : wsel == 2 ? vw : ow;
    dst = wsel == 0 ? qwb : wsel == 1 ? kwb : wsel == 2 ? vwb : owb;
    base = (size_t)wb << 11;
  }
  size_t i = base + ((size_t)threadIdx.x << 3);
  float4 a = *(const float4*)(src + i);
  float4 b = *(const float4*)(src + i + 4);
  u16x8 o;
  o[0] = f2b(a.x); o[1] = f2b(a.y); o[2] = f2b(a.z); o[3] = f2b(a.w);
  o[4] = f2b(b.x); o[5] = f2b(b.y); o[6] = f2b(b.z); o[7] = f2b(b.w);
  *(u16x8*)(dst + i) = o;
}

// 256x256-tile bf16 GEMM, 8 waves (2Mx4N), BK=32, ring-of-4 LDS slots,
// 3-deep prefetch, counted vmcnt(8) gate, XOR-swizzled LDS (slot-correct:
// x = l4 ^ ((row>>1)&3)), 2 MFMA phases/K-step. K fixed = 2048 (64 steps).
// C[M,N] = act(A[M,K] @ B[N,K]^T + bias[N]).
template<int QKV, int OUT_BF16>
__global__ __launch_bounds__(512, 2) void gemm256(
    const unsigned short* __restrict__ A,
    const unsigned short* __restrict__ B0,
    const unsigned short* __restrict__ B1,
    const unsigned short* __restrict__ B2,
    const float* __restrict__ bias0,
    const float* __restrict__ bias1,
    const float* __restrict__ bias2,
    void* __restrict__ Cp,
    int mtile, int astr, int ostr)
{
  __shared__ unsigned short lds[65536];   // 128 KiB: [slot:4][op:2][8192]
  const int tid = threadIdx.x;
  const int lane = tid & 63, wid = tid >> 6;
  const int wr = wid >> 2, wc = wid & 3;
  const int l15 = lane & 15, l4 = lane >> 4;

  // bijective XCD swizzle (grid % 8 == 0), bn-outer / bm-inner
  const int cpx = (int)gridDim.x >> 3;
  const int bidx = (int)blockIdx.x;
  const int wg = (bidx & 7) * cpx + (bidx >> 3);
  const int bm = (wg % mtile) << 8;
  const int bn = (wg / mtile) << 8;

  const unsigned short* Bp = B0;
  const float* bias = bias0;
  bool act = false;
  int bnw = bn;
  if (QKV) {
    int seg = bn >> 11;
    Bp = seg == 0 ? B0 : (seg == 1 ? B1 : B2);
    bias = seg == 0 ? bias0 : (seg == 1 ? bias1 : bias2);
    act = seg < 2;
    bnw = bn & 2047;
  }

  // staging: wave stages chunks {2*wid, 2*wid+1} of A and B. chunk = 16 rows
  // x 32 cols (1024B). lane: row = lane>>2, 16B col-slot = lane&3, source col
  // inverse-swizzled so linear LDS write + swizzled read are consistent.
  const int c0 = wid << 1;
  const int srow = lane >> 2;
  const int scol = (((lane & 3) ^ ((srow >> 1) & 3)) << 3);
  const unsigned short* Asrc0 = A + (size_t)(bm + (c0 << 4) + srow) * astr + scol;
  const unsigned short* Asrc1 = Asrc0 + (size_t)16 * astr;
  const unsigned short* Bsrc0 = Bp + (size_t)(bnw + (c0 << 4) + srow) * HIDC + scol;
  const unsigned short* Bsrc1 = Bsrc0 + (size_t)16 * HIDC;
  const int adst = c0 << 9;               // ushort idx within op region

  // fragment read offsets (swizzled): row*32 + ((l4 ^ ((row>>1)&3))<<3)
  const int xa = ((l4 ^ ((l15 >> 1) & 3)) << 3);
  const int abase = ((wr << 7) + l15) * 32 + xa;
  const int bbase = 8192 + ((wc << 6) + l15) * 32 + xa;

  f32x4 acc[8][4] = {};

#define STAGE_A(s_) { const int sl_ = ((s_) & 3) << 14; const int kt_ = (s_) << 5; \
    gload_lds16(Asrc0 + kt_, &lds[sl_ + adst]); \
    gload_lds16(Asrc1 + kt_, &lds[sl_ + adst + 512]); }
#define STAGE_B(s_) { const int sl_ = ((s_) & 3) << 14; const int kt_ = (s_) << 5; \
    gload_lds16(Bsrc0 + kt_, &lds[sl_ + 8192 + adst]); \
    gload_lds16(Bsrc1 + kt_, &lds[sl_ + 8192 + adst + 512]); }

#define DO_STEP(s_, STG, GATE) { \
    const int sl = ((s_) & 3) << 14; \
    s16x8 a[8], bl[2], bh[2]; \
    _Pragma("unroll") for (int mf = 0; mf < 8; ++mf) \
      a[mf] = *(const s16x8*)&lds[sl + abase + (mf << 9)]; \
    bl[0] = *(const s16x8*)&lds[sl + bbase]; \
    bl[1] = *(const s16x8*)&lds[sl + bbase + 512]; \
    if (STG) STAGE_A((s_) + 3); \
    __builtin_amdgcn_s_barrier(); \
    __builtin_amdgcn_s_setprio(1); \
    _Pragma("unroll") for (int mf = 0; mf < 8; ++mf) { \
      acc[mf][0] = __builtin_amdgcn_mfma_f32_16x16x32_bf16(a[mf], bl[0], acc[mf][0], 0, 0, 0); \
      acc[mf][1] = __builtin_amdgcn_mfma_f32_16x16x32_bf16(a[mf], bl[1], acc[mf][1], 0, 0, 0); } \
    __builtin_amdgcn_s_setprio(0); \
    __builtin_amdgcn_s_barrier(); \
    bh[0] = *(const s16x8*)&lds[sl + bbase + 1024]; \
    bh[1] = *(const s16x8*)&lds[sl + bbase + 1536]; \
    if (STG) STAGE_B((s_) + 3); \
    __builtin_amdgcn_s_barrier(); \
    __builtin_amdgcn_s_setprio(1); \
    _Pragma("unroll") for (int mf = 0; mf < 8; ++mf) { \
      acc[mf][2] = __builtin_amdgcn_mfma_f32_16x16x32_bf16(a[mf], bh[0], acc[mf][2], 0, 0, 0); \
      acc[mf][3] = __builtin_amdgcn_mfma_f32_16x16x32_bf16(a[mf], bh[1], acc[mf][3], 0, 0, 0); } \
    __builtin_amdgcn_s_setprio(0); \
    if ((GATE) == 8)      { asm volatile("s_waitcnt vmcnt(8)" ::: "memory"); } \
    else if ((GATE) == 4) { asm volatile("s_waitcnt vmcnt(4)" ::: "memory"); } \
    else if ((GATE) == 0) { asm volatile("s_waitcnt vmcnt(0)" ::: "memory"); } \
    __builtin_amdgcn_s_barrier(); \
    __builtin_amdgcn_sched_barrier(0); \
  }

  // prologue: stage slots 0,1,2 (12 loads/wave); gate so slot 0 is resident
  STAGE_A(0); STAGE_B(0);
  STAGE_A(1); STAGE_B(1);
  STAGE_A(2); STAGE_B(2);
  asm volatile("s_waitcnt vmcnt(8)" ::: "memory");
  __builtin_amdgcn_s_barrier();
  __builtin_amdgcn_sched_barrier(0);

  for (int s = 0; s < 61; ++s) DO_STEP(s, 1, 8);
  DO_STEP(61, 0, 4);
  DO_STEP(62, 0, 0);
  DO_STEP(63, 0, -1);

#undef DO_STEP
#undef STAGE_A
#undef STAGE_B

  #pragma unroll
  for (int nf = 0; nf < 4; ++nf) {
    const int colw = (wc << 6) + (nf << 4) + l15;
    const float bv = bias[bnw + colw];
    #pragma unroll
    for (int mf = 0; mf < 8; ++mf) {
      #pragma unroll
      for (int r = 0; r < 4; ++r) {
        const int row = bm + (wr << 7) + (mf << 4) + (l4 << 2) + r;
        float v = acc[mf][nf][r] + bv;
        if (QKV) { if (act) v = (v > 0.f) ? (v + 1.f) : __expf(v); }
        const size_t off = (size_t)row * ostr + bn + colw;
        if (OUT_BF16) ((unsigned short*)Cp)[off] = f2b(v);
        else          ((float*)Cp)[off] = v;
      }
    }
  }
}

// kv partials over 8 S-chunks (deterministic, no atomics).
__global__ __launch_bounds__(256) void kv_partial(
    const unsigned short* __restrict__ kp, const unsigned short* __restrict__ vv,
    float* __restrict__ kvp, float* __restrict__ ksp)
{
  const int bh = blockIdx.x >> 3;
  const int chunk = blockIdx.x & 7;
  const int b = bh >> 4, h = bh & 15;
  const int tid = threadIdx.x;
  const int td = tid >> 4, te = tid & 15;

  __shared__ float kpl[32][128];
  __shared__ float vl[32][132];

  float acc[8][8] = {};
  float ks[8] = {};

  const size_t rowbase = (size_t)b * NS * QSTR + (size_t)h * HDIM;
  const int s0 = chunk * 512;

  for (int st = 0; st < 512; st += 32) {
    __syncthreads();
    #pragma unroll
    for (int i = 0; i < 2; ++i) {
      int idx = tid + (i << 8);
      int row = idx >> 4, q = idx & 15;
      size_t g = rowbase + (size_t)(s0 + st + row) * QSTR + (q << 3);
      u16x8 k8 = *(const u16x8*)(kp + g);
      u16x8 v8 = *(const u16x8*)(vv + g);
      float tk[8], tv[8];
      #pragma unroll
      for (int j = 0; j < 8; ++j) { tk[j] = b2f(k8[j]); tv[j] = b2f(v8[j]); }
      *(float4*)&kpl[row][(q << 3)]     = make_float4(tk[0], tk[1], tk[2], tk[3]);
      *(float4*)&kpl[row][(q << 3) + 4] = make_float4(tk[4], tk[5], tk[6], tk[7]);
      *(float4*)&vl[row][(q << 3)]      = make_float4(tv[0], tv[1], tv[2], tv[3]);
      *(float4*)&vl[row][(q << 3) + 4]  = make_float4(tv[4], tv[5], tv[6], tv[7]);
    }
    __syncthreads();
    #pragma unroll 4
    for (int s = 0; s < 32; ++s) {
      float kd[8], ve[8];
      *(float4*)&kd[0] = *(const float4*)&kpl[s][td << 3];
      *(float4*)&kd[4] = *(const float4*)&kpl[s][(td << 3) + 4];
      *(float4*)&ve[0] = *(const float4*)&vl[s][te << 3];
      *(float4*)&ve[4] = *(const float4*)&vl[s][(te << 3) + 4];
      if (te == 0) {
        #pragma unroll
        for (int i = 0; i < 8; ++i) ks[i] += kd[i];
      }
      #pragma unroll
      for (int i = 0; i < 8; ++i)
        #pragma unroll
        for (int j = 0; j < 8; ++j)
          acc[i][j] += kd[i] * ve[j];
    }
  }

  float* outp = kvp + ((size_t)(chunk * 64 + bh) << 14);
  #pragma unroll
  for (int j = 0; j < 8; ++j) {
    int e = (te << 3) + j;
    float r0[8];
    #pragma unroll
    for (int i = 0; i < 8; ++i) r0[i] = acc[i][j];
    *(float4*)&outp[(size_t)e * HDIM + (td << 3)]     = *(float4*)&r0[0];
    *(float4*)&outp[(size_t)e * HDIM + (td << 3) + 4] = *(float4*)&r0[4];
  }
  if (te == 0) {
    float* kso = ksp + ((size_t)(chunk * 64 + bh) << 7) + (td << 3);
    #pragma unroll
    for (int i = 0; i < 8; ++i) kso[i] = ks[i];
  }
}

__global__ __launch_bounds__(256) void kv_reduce(
    const float* __restrict__ kvp, float* __restrict__ kvT)
{
  int i = blockIdx.x * 256 + threadIdx.x;
  float s = 0.f;
  #pragma unroll
  for (int c = 0; c < 8; ++c) s += kvp[(size_t)c * (64 * 16384) + i];
  kvT[i] = s;
}

// attn[s,e] = (qp[s,:] . kvT[e,:]) / (z[s]+eps); qp = q cols of qkv, out -> v cols.
__global__ __launch_bounds__(256) void attn_ker(
    const unsigned short* __restrict__ qp, const float* __restrict__ kvT,
    const float* __restrict__ ksp, unsigned short* __restrict__ attn)
{
  const int bh = blockIdx.x >> 5, stile = blockIdx.x & 31;
  const int b = bh >> 4, h = bh & 15;
  const int tid = threadIdx.x;
  const int lane = tid & 63, w = tid >> 6;
  const int l15 = lane & 15, l4 = lane >> 4;

  __shared__ unsigned short Qs[128][136];
  __shared__ unsigned short Ks[128][136];
  __shared__ float ksl[128];
  __shared__ float zs[128];

  const size_t qbase = ((size_t)b * NS + (size_t)stile * 128) * QSTR + (size_t)h * HDIM;

  #pragma unroll
  for (int i = 0; i < 8; ++i) {
    int idx = tid + (i << 8);
    int row = idx >> 4, q = idx & 15;
    u16x8 v8 = *(const u16x8*)(qp + qbase + (size_t)row * QSTR + (q << 3));
    *(u16x8*)&Qs[row][q << 3] = v8;
  }
  const float* kvb = kvT + ((size_t)bh << 14);
  #pragma unroll
  for (int i = 0; i < 16; ++i) {
    int idx = tid + (i << 8);
    int row = idx >> 5, q = idx & 31;
    float4 v4 = *(const float4*)(kvb + (size_t)row * HDIM + (q << 2));
    ushort4 w4; w4.x = f2b(v4.x); w4.y = f2b(v4.y); w4.z = f2b(v4.z); w4.w = f2b(v4.w);
    *(ushort4*)&Ks[row][q << 2] = w4;
  }
  if (tid < 128) {
    float s = 0.f;
    #pragma unroll
    for (int c = 0; c < 8; ++c) s += ksp[((size_t)(c * 64 + bh) << 7) + tid];
    ksl[tid] = s;
  }
  __syncthreads();
  if (tid < 128) {
    float z = 0.f;
    #pragma unroll
    for (int dq = 0; dq < 16; ++dq) {
      u16x8 qv = *(const u16x8*)&Qs[tid][dq << 3];
      #pragma unroll
      for (int j = 0; j < 8; ++j) z += b2f(qv[j]) * ksl[(dq << 3) + j];
    }
    zs[tid] = 1.f / (z + EPSV);
  }
  __syncthreads();

  f32x4 acc[2][8] = {};
  #pragma unroll
  for (int kk = 0; kk < 4; ++kk) {
    s16x8 a[2], bb[8];
    #pragma unroll
    for (int mf = 0; mf < 2; ++mf)
      a[mf] = *(const s16x8*)&Qs[(w << 5) + (mf << 4) + l15][(kk << 5) + (l4 << 3)];
    #pragma unroll
    for (int nf = 0; nf < 8; ++nf)
      bb[nf] = *(const s16x8*)&Ks[(nf << 4) + l15][(kk << 5) + (l4 << 3)];
    #pragma unroll
    for (int mf = 0; mf < 2; ++mf)
      #pragma unroll
      for (int nf = 0; nf < 8; ++nf)
        acc[mf][nf] = __builtin_amdgcn_mfma_f32_16x16x32_bf16(a[mf], bb[nf], acc[mf][nf], 0, 0, 0);
  }

  #pragma unroll
  for (int mf = 0; mf < 2; ++mf) {
    #pragma unroll
    for (int r = 0; r < 4; ++r) {
      const int rl = (w << 5) + (mf << 4) + (l4 << 2) + r;
      const float zi = zs[rl];
      #pragma unroll
      for (int nf = 0; nf < 8; ++nf) {
        const int e = (nf << 4) + l15;
        attn[qbase + (size_t)rl * QSTR + e] = f2b(acc[mf][nf][r] * zi);
      }
    }
  }
}

extern "C" void kernel_launch(void* const* d_in, const int* in_sizes, int n_in,
                              void* d_out, int out_size, void* d_ws, size_t ws_size,
                              hipStream_t stream) {
  const float* hs = (const float*)d_in[0];
  const float* qw = (const float*)d_in[1];
  const float* qb = (const float*)d_in[2];
  const float* kw = (const float*)d_in[3];
  const float* kb = (const float*)d_in[4];
  const float* vw = (const float*)d_in[5];
  const float* vb = (const float*)d_in[6];
  const float* ow = (const float*)d_in[7];
  const float* ob = (const float*)d_in[8];

  char* w = (char*)d_ws;
  unsigned short* hsb = (unsigned short*)(w);                  // 64 MiB (dead after QKV gemm)
  unsigned short* qwb = (unsigned short*)(w + 67108864);       // 8 MiB each
  unsigned short* kwb = (unsigned short*)(w + 75497472);
  unsigned short* vwb = (unsigned short*)(w + 83886080);
  unsigned short* owb = (unsigned short*)(w + 92274688);
  unsigned short* qkv = (unsigned short*)(w + 100663296);      // 192 MiB, row stride 6144
  // aliases over the dead hsb region:
  float* kvp = (float*)(w);                                    // 32 MiB
  float* ksp = (float*)(w + 33554432);                         // 256 KiB
  float* kvT = (float*)(w + 33816576);                         // 4 MiB

  convert_all<<<dim3(24576), dim3(256), 0, stream>>>(hs, qw, kw, vw, ow, hsb, qwb, kwb, vwb, owb);
  // QKV fused: M=16384, N=6144 (q|k|v columns), elu+1 on q,k
  gemm256<1, 1><<<dim3(24 * 64), dim3(512), 0, stream>>>(
      hsb, qwb, kwb, vwb, qb, kb, vb, qkv, 64, HIDC, QSTR);
  kv_partial<<<dim3(512), dim3(256), 0, stream>>>(qkv + 2048, qkv + 4096, kvp, ksp);
  kv_reduce<<<dim3(4096), dim3(256), 0, stream>>>(kvp, kvT);
  attn_ker<<<dim3(2048), dim3(256), 0, stream>>>(qkv, kvT, ksp, qkv + 4096);
  // final: out = attn @ o_w^T + o_b, A = v-columns of qkv (astr=QSTR), fp32 out
  gemm256<0, 0><<<dim3(8 * 64), dim3(512), 0, stream>>>(
      qkv + 4096, owb, owb, owb, ob, ob, ob, d_out, 64, QSTR, HIDC);
}

// Round 5
// 783.813 us; speedup vs baseline: 2.9561x; 1.0598x over previous
//
#include <hip/hip_runtime.h>
#include <hip/hip_bf16.h>

#define HIDC 2048
#define NHEADS 16
#define HDIM 128
#define NB 4
#define NS 4096
#define NROWS (NB*NS)
#define QSTR 6144
#define EPSV 1e-6f

typedef __attribute__((ext_vector_type(8))) short s16x8;
typedef __attribute__((ext_vector_type(4))) float f32x4;
typedef __attribute__((ext_vector_type(8))) unsigned short u16x8;

static __device__ __forceinline__ unsigned short f2b(float f) {
  unsigned int u = __float_as_uint(f);
  u += 0x7fffu + ((u >> 16) & 1u);
  return (unsigned short)(u >> 16);
}
static __device__ __forceinline__ float b2f(unsigned short h) {
  return __uint_as_float(((unsigned int)h) << 16);
}

static __device__ __forceinline__ void gload_lds16(const unsigned short* g, unsigned short* l) {
  __builtin_amdgcn_global_load_lds(
      (const __attribute__((address_space(1))) void*)g,
      (__attribute__((address_space(3))) void*)l, 16, 0, 0);
}

// fp32 -> bf16 conversion for hs (16384 blocks) + 4 weights (2048 blocks each)
__global__ __launch_bounds__(256) void convert_all(
    const float* __restrict__ hs, const float* __restrict__ qw,
    const float* __restrict__ kw, const float* __restrict__ vw,
    const float* __restrict__ ow,
    unsigned short* __restrict__ hsb, unsigned short* __restrict__ qwb,
    unsigned short* __restrict__ kwb, unsigned short* __restrict__ vwb,
    unsigned short* __restrict__ owb)
{
  int bid = blockIdx.x;
  const float* src; unsigned short* dst; size_t base;
  if (bid < 16384) { src = hs; dst = hsb; base = (size_t)bid << 11; }
  else {
    int t = bid - 16384; int wsel = t >> 11; int wb = t & 2047;
    src = wsel == 0 ? qw : wsel == 1 ? kw : wsel == 2 ? vw : ow;
    dst = wsel == 0 ? qwb : wsel == 1 ? kwb : wsel == 2 ? vwb : owb;
    base = (size_t)wb << 11;
  }
  size_t i = base + ((size_t)threadIdx.x << 3);
  float4 a = *(const float4*)(src + i);
  float4 b = *(const float4*)(src + i + 4);
  u16x8 o;
  o[0] = f2b(a.x); o[1] = f2b(a.y); o[2] = f2b(a.z); o[3] = f2b(a.w);
  o[4] = f2b(b.x); o[5] = f2b(b.y); o[6] = f2b(b.z); o[7] = f2b(b.w);
  *(u16x8*)(dst + i) = o;
}

// 256x256-tile bf16 GEMM, 8 waves (2Mx4N), BK=32, ring-of-4 LDS slots,
// 3-deep prefetch, counted vmcnt(8) gates. m201-style phase microstructure:
// phase A: {8 ds_read, stage-A, bar, lgkmcnt(0), 16 MFMA, bar}
// phase B: {4 ds_read, stage-B, bar, lgkmcnt(0), 16 MFMA, gate, bar}
// L2 chunking: 4 bm-tiles x all bn per chunk. K fixed = 2048 (64 steps).
template<int QKV, int OUT_BF16>
__global__ __launch_bounds__(512, 2) void gemm256(
    const unsigned short* __restrict__ A,
    const unsigned short* __restrict__ B0,
    const unsigned short* __restrict__ B1,
    const unsigned short* __restrict__ B2,
    const float* __restrict__ bias0,
    const float* __restrict__ bias1,
    const float* __restrict__ bias2,
    void* __restrict__ Cp,
    int ntile, int astr, int ostr)
{
  __shared__ unsigned short lds[65536];   // 128 KiB: [slot:4][op:2][8192]
  const int tid = threadIdx.x;
  const int lane = tid & 63, wid = tid >> 6;
  const int wr = wid >> 2, wc = wid & 3;
  const int l15 = lane & 15, l4 = lane >> 4;

  // bijective XCD swizzle (grid % 8 == 0) + L2 chunking: 4 bm x all bn
  const int cpx = (int)gridDim.x >> 3;
  const int bidx = (int)blockIdx.x;
  const int wg = (bidx & 7) * cpx + (bidx >> 3);
  const int csz = ntile << 2;
  const int chunk = wg / csz;
  const int t = wg % csz;
  const int bm = ((chunk << 2) + (t & 3)) << 8;
  const int bn = (t >> 2) << 8;

  const unsigned short* Bp = B0;
  const float* bias = bias0;
  bool act = false;
  int bnw = bn;
  if (QKV) {
    int seg = bn >> 11;
    Bp = seg == 0 ? B0 : (seg == 1 ? B1 : B2);
    bias = seg == 0 ? bias0 : (seg == 1 ? bias1 : bias2);
    act = seg < 2;
    bnw = bn & 2047;
  }

  // staging: wave stages chunks {2*wid, 2*wid+1} of A and B. chunk = 16 rows
  // x 32 cols (1024B). source col inverse-swizzled (linear LDS write +
  // swizzled read = consistent involution).
  const int c0 = wid << 1;
  const int srow = lane >> 2;
  const int scol = (((lane & 3) ^ ((srow >> 1) & 3)) << 3);
  const unsigned short* Asrc0 = A + (size_t)(bm + (c0 << 4) + srow) * astr + scol;
  const unsigned short* Asrc1 = Asrc0 + (size_t)16 * astr;
  const unsigned short* Bsrc0 = Bp + (size_t)(bnw + (c0 << 4) + srow) * HIDC + scol;
  const unsigned short* Bsrc1 = Bsrc0 + (size_t)16 * HIDC;
  const int adst = c0 << 9;               // ushort idx within op region

  // fragment read offsets (swizzled): row*32 + ((l4 ^ ((row>>1)&3))<<3)
  const int xa = ((l4 ^ ((l15 >> 1) & 3)) << 3);
  const int abase = ((wr << 7) + l15) * 32 + xa;
  const int bbase = 8192 + ((wc << 6) + l15) * 32 + xa;

  f32x4 acc[8][4] = {};

#define STAGE_A(s_) { const int sl_ = ((s_) & 3) << 14; const int kt_ = (s_) << 5; \
    gload_lds16(Asrc0 + kt_, &lds[sl_ + adst]); \
    gload_lds16(Asrc1 + kt_, &lds[sl_ + adst + 512]); }
#define STAGE_B(s_) { const int sl_ = ((s_) & 3) << 14; const int kt_ = (s_) << 5; \
    gload_lds16(Bsrc0 + kt_, &lds[sl_ + 8192 + adst]); \
    gload_lds16(Bsrc1 + kt_, &lds[sl_ + 8192 + adst + 512]); }

#define MM4(ai_, r_) { \
    acc[r_][0] = __builtin_amdgcn_mfma_f32_16x16x32_bf16(ai_, b0, acc[r_][0], 0, 0, 0); \
    acc[r_][1] = __builtin_amdgcn_mfma_f32_16x16x32_bf16(ai_, b1, acc[r_][1], 0, 0, 0); \
    acc[r_][2] = __builtin_amdgcn_mfma_f32_16x16x32_bf16(ai_, b2, acc[r_][2], 0, 0, 0); \
    acc[r_][3] = __builtin_amdgcn_mfma_f32_16x16x32_bf16(ai_, b3, acc[r_][3], 0, 0, 0); }

#define DO_STEP(s_, STG, GATE) { \
    const int sl = ((s_) & 3) << 14; \
    /* ---- phase A: B-frags + a[0..3] ---- */ \
    s16x8 b0 = *(const s16x8*)&lds[sl + bbase]; \
    s16x8 b1 = *(const s16x8*)&lds[sl + bbase + 512]; \
    s16x8 b2 = *(const s16x8*)&lds[sl + bbase + 1024]; \
    s16x8 b3 = *(const s16x8*)&lds[sl + bbase + 1536]; \
    s16x8 a0 = *(const s16x8*)&lds[sl + abase]; \
    s16x8 a1 = *(const s16x8*)&lds[sl + abase + 512]; \
    s16x8 a2 = *(const s16x8*)&lds[sl + abase + 1024]; \
    s16x8 a3 = *(const s16x8*)&lds[sl + abase + 1536]; \
    if (STG) STAGE_A((s_) + 3); \
    __builtin_amdgcn_s_barrier(); \
    asm volatile("s_waitcnt lgkmcnt(0)" ::: "memory"); \
    __builtin_amdgcn_s_setprio(1); \
    MM4(a0, 0) MM4(a1, 1) MM4(a2, 2) MM4(a3, 3) \
    __builtin_amdgcn_s_setprio(0); \
    __builtin_amdgcn_s_barrier(); \
    /* ---- phase B: a[4..7] ---- */ \
    s16x8 a4 = *(const s16x8*)&lds[sl + abase + 2048]; \
    s16x8 a5 = *(const s16x8*)&lds[sl + abase + 2560]; \
    s16x8 a6 = *(const s16x8*)&lds[sl + abase + 3072]; \
    s16x8 a7 = *(const s16x8*)&lds[sl + abase + 3584]; \
    if (STG) STAGE_B((s_) + 3); \
    __builtin_amdgcn_s_barrier(); \
    asm volatile("s_waitcnt lgkmcnt(0)" ::: "memory"); \
    __builtin_amdgcn_s_setprio(1); \
    MM4(a4, 4) MM4(a5, 5) MM4(a6, 6) MM4(a7, 7) \
    __builtin_amdgcn_s_setprio(0); \
    if ((GATE) == 8)      { asm volatile("s_waitcnt vmcnt(8)" ::: "memory"); } \
    else if ((GATE) == 4) { asm volatile("s_waitcnt vmcnt(4)" ::: "memory"); } \
    else if ((GATE) == 0) { asm volatile("s_waitcnt vmcnt(0)" ::: "memory"); } \
    __builtin_amdgcn_s_barrier(); \
  }

  // prologue: stage slots 0,1,2 (12 loads/wave); gate so slot 0 is resident
  STAGE_A(0); STAGE_B(0);
  STAGE_A(1); STAGE_B(1);
  STAGE_A(2); STAGE_B(2);
  asm volatile("s_waitcnt vmcnt(8)" ::: "memory");
  __builtin_amdgcn_s_barrier();

  for (int s = 0; s < 61; ++s) DO_STEP(s, 1, 8);
  DO_STEP(61, 0, 4);
  DO_STEP(62, 0, 0);
  DO_STEP(63, 0, -1);

#undef DO_STEP
#undef MM4
#undef STAGE_A
#undef STAGE_B

  #pragma unroll
  for (int nf = 0; nf < 4; ++nf) {
    const int colw = (wc << 6) + (nf << 4) + l15;
    const float bv = bias[bnw + colw];
    #pragma unroll
    for (int mf = 0; mf < 8; ++mf) {
      #pragma unroll
      for (int r = 0; r < 4; ++r) {
        const int row = bm + (wr << 7) + (mf << 4) + (l4 << 2) + r;
        float v = acc[mf][nf][r] + bv;
        if (QKV) { if (act) v = (v > 0.f) ? (v + 1.f) : __expf(v); }
        const size_t off = (size_t)row * ostr + bn + colw;
        if (OUT_BF16) ((unsigned short*)Cp)[off] = f2b(v);
        else          ((float*)Cp)[off] = v;
      }
    }
  }
}

// kv partials over 8 S-chunks (deterministic, no atomics).
__global__ __launch_bounds__(256) void kv_partial(
    const unsigned short* __restrict__ kp, const unsigned short* __restrict__ vv,
    float* __restrict__ kvp, float* __restrict__ ksp)
{
  const int bh = blockIdx.x >> 3;
  const int chunk = blockIdx.x & 7;
  const int b = bh >> 4, h = bh & 15;
  const int tid = threadIdx.x;
  const int td = tid >> 4, te = tid & 15;

  __shared__ float kpl[32][128];
  __shared__ float vl[32][132];

  float acc[8][8] = {};
  float ks[8] = {};

  const size_t rowbase = (size_t)b * NS * QSTR + (size_t)h * HDIM;
  const int s0 = chunk * 512;

  for (int st = 0; st < 512; st += 32) {
    __syncthreads();
    #pragma unroll
    for (int i = 0; i < 2; ++i) {
      int idx = tid + (i << 8);
      int row = idx >> 4, q = idx & 15;
      size_t g = rowbase + (size_t)(s0 + st + row) * QSTR + (q << 3);
      u16x8 k8 = *(const u16x8*)(kp + g);
      u16x8 v8 = *(const u16x8*)(vv + g);
      float tk[8], tv[8];
      #pragma unroll
      for (int j = 0; j < 8; ++j) { tk[j] = b2f(k8[j]); tv[j] = b2f(v8[j]); }
      *(float4*)&kpl[row][(q << 3)]     = make_float4(tk[0], tk[1], tk[2], tk[3]);
      *(float4*)&kpl[row][(q << 3) + 4] = make_float4(tk[4], tk[5], tk[6], tk[7]);
      *(float4*)&vl[row][(q << 3)]      = make_float4(tv[0], tv[1], tv[2], tv[3]);
      *(float4*)&vl[row][(q << 3) + 4]  = make_float4(tv[4], tv[5], tv[6], tv[7]);
    }
    __syncthreads();
    #pragma unroll 4
    for (int s = 0; s < 32; ++s) {
      float kd[8], ve[8];
      *(float4*)&kd[0] = *(const float4*)&kpl[s][td << 3];
      *(float4*)&kd[4] = *(const float4*)&kpl[s][(td << 3) + 4];
      *(float4*)&ve[0] = *(const float4*)&vl[s][te << 3];
      *(float4*)&ve[4] = *(const float4*)&vl[s][(te << 3) + 4];
      if (te == 0) {
        #pragma unroll
        for (int i = 0; i < 8; ++i) ks[i] += kd[i];
      }
      #pragma unroll
      for (int i = 0; i < 8; ++i)
        #pragma unroll
        for (int j = 0; j < 8; ++j)
          acc[i][j] += kd[i] * ve[j];
    }
  }

  float* outp = kvp + ((size_t)(chunk * 64 + bh) << 14);
  #pragma unroll
  for (int j = 0; j < 8; ++j) {
    int e = (te << 3) + j;
    float r0[8];
    #pragma unroll
    for (int i = 0; i < 8; ++i) r0[i] = acc[i][j];
    *(float4*)&outp[(size_t)e * HDIM + (td << 3)]     = *(float4*)&r0[0];
    *(float4*)&outp[(size_t)e * HDIM + (td << 3) + 4] = *(float4*)&r0[4];
  }
  if (te == 0) {
    float* kso = ksp + ((size_t)(chunk * 64 + bh) << 7) + (td << 3);
    #pragma unroll
    for (int i = 0; i < 8; ++i) kso[i] = ks[i];
  }
}

__global__ __launch_bounds__(256) void kv_reduce(
    const float* __restrict__ kvp, float* __restrict__ kvT)
{
  int i = blockIdx.x * 256 + threadIdx.x;
  float s = 0.f;
  #pragma unroll
  for (int c = 0; c < 8; ++c) s += kvp[(size_t)c * (64 * 16384) + i];
  kvT[i] = s;
}

// attn[s,e] = (qp[s,:] . kvT[e,:]) / (z[s]+eps); qp = q cols of qkv, out -> v cols.
__global__ __launch_bounds__(256) void attn_ker(
    const unsigned short* __restrict__ qp, const float* __restrict__ kvT,
    const float* __restrict__ ksp, unsigned short* __restrict__ attn)
{
  const int bh = blockIdx.x >> 5, stile = blockIdx.x & 31;
  const int b = bh >> 4, h = bh & 15;
  const int tid = threadIdx.x;
  const int lane = tid & 63, w = tid >> 6;
  const int l15 = lane & 15, l4 = lane >> 4;

  __shared__ unsigned short Qs[128][136];
  __shared__ unsigned short Ks[128][136];
  __shared__ float ksl[128];
  __shared__ float zs[128];

  const size_t qbase = ((size_t)b * NS + (size_t)stile * 128) * QSTR + (size_t)h * HDIM;

  #pragma unroll
  for (int i = 0; i < 8; ++i) {
    int idx = tid + (i << 8);
    int row = idx >> 4, q = idx & 15;
    u16x8 v8 = *(const u16x8*)(qp + qbase + (size_t)row * QSTR + (q << 3));
    *(u16x8*)&Qs[row][q << 3] = v8;
  }
  const float* kvb = kvT + ((size_t)bh << 14);
  #pragma unroll
  for (int i = 0; i < 16; ++i) {
    int idx = tid + (i << 8);
    int row = idx >> 5, q = idx & 31;
    float4 v4 = *(const float4*)(kvb + (size_t)row * HDIM + (q << 2));
    ushort4 w4; w4.x = f2b(v4.x); w4.y = f2b(v4.y); w4.z = f2b(v4.z); w4.w = f2b(v4.w);
    *(ushort4*)&Ks[row][q << 2] = w4;
  }
  if (tid < 128) {
    float s = 0.f;
    #pragma unroll
    for (int c = 0; c < 8; ++c) s += ksp[((size_t)(c * 64 + bh) << 7) + tid];
    ksl[tid] = s;
  }
  __syncthreads();
  if (tid < 128) {
    float z = 0.f;
    #pragma unroll
    for (int dq = 0; dq < 16; ++dq) {
      u16x8 qv = *(const u16x8*)&Qs[tid][dq << 3];
      #pragma unroll
      for (int j = 0; j < 8; ++j) z += b2f(qv[j]) * ksl[(dq << 3) + j];
    }
    zs[tid] = 1.f / (z + EPSV);
  }
  __syncthreads();

  f32x4 acc[2][8] = {};
  #pragma unroll
  for (int kk = 0; kk < 4; ++kk) {
    s16x8 a[2], bb[8];
    #pragma unroll
    for (int mf = 0; mf < 2; ++mf)
      a[mf] = *(const s16x8*)&Qs[(w << 5) + (mf << 4) + l15][(kk << 5) + (l4 << 3)];
    #pragma unroll
    for (int nf = 0; nf < 8; ++nf)
      bb[nf] = *(const s16x8*)&Ks[(nf << 4) + l15][(kk << 5) + (l4 << 3)];
    #pragma unroll
    for (int mf = 0; mf < 2; ++mf)
      #pragma unroll
      for (int nf = 0; nf < 8; ++nf)
        acc[mf][nf] = __builtin_amdgcn_mfma_f32_16x16x32_bf16(a[mf], bb[nf], acc[mf][nf], 0, 0, 0);
  }

  #pragma unroll
  for (int mf = 0; mf < 2; ++mf) {
    #pragma unroll
    for (int r = 0; r < 4; ++r) {
      const int rl = (w << 5) + (mf << 4) + (l4 << 2) + r;
      const float zi = zs[rl];
      #pragma unroll
      for (int nf = 0; nf < 8; ++nf) {
        const int e = (nf << 4) + l15;
        attn[qbase + (size_t)rl * QSTR + e] = f2b(acc[mf][nf][r] * zi);
      }
    }
  }
}

extern "C" void kernel_launch(void* const* d_in, const int* in_sizes, int n_in,
                              void* d_out, int out_size, void* d_ws, size_t ws_size,
                              hipStream_t stream) {
  const float* hs = (const float*)d_in[0];
  const float* qw = (const float*)d_in[1];
  const float* qb = (const float*)d_in[2];
  const float* kw = (const float*)d_in[3];
  const float* kb = (const float*)d_in[4];
  const float* vw = (const float*)d_in[5];
  const float* vb = (const float*)d_in[6];
  const float* ow = (const float*)d_in[7];
  const float* ob = (const float*)d_in[8];

  char* w = (char*)d_ws;
  unsigned short* hsb = (unsigned short*)(w);                  // 64 MiB (dead after QKV gemm)
  unsigned short* qwb = (unsigned short*)(w + 67108864);       // 8 MiB each
  unsigned short* kwb = (unsigned short*)(w + 75497472);
  unsigned short* vwb = (unsigned short*)(w + 83886080);
  unsigned short* owb = (unsigned short*)(w + 92274688);
  unsigned short* qkv = (unsigned short*)(w + 100663296);      // 192 MiB, row stride 6144
  // aliases over the dead hsb region:
  float* kvp = (float*)(w);                                    // 32 MiB
  float* ksp = (float*)(w + 33554432);                         // 256 KiB
  float* kvT = (float*)(w + 33816576);                         // 4 MiB

  convert_all<<<dim3(24576), dim3(256), 0, stream>>>(hs, qw, kw, vw, ow, hsb, qwb, kwb, vwb, owb);
  // QKV fused: M=16384, N=6144 (q|k|v columns), elu+1 on q,k
  gemm256<1, 1><<<dim3(24 * 64), dim3(512), 0, stream>>>(
      hsb, qwb, kwb, vwb, qb, kb, vb, qkv, 24, HIDC, QSTR);
  kv_partial<<<dim3(512), dim3(256), 0, stream>>>(qkv + 2048, qkv + 4096, kvp, ksp);
  kv_reduce<<<dim3(4096), dim3(256), 0, stream>>>(kvp, kvT);
  attn_ker<<<dim3(2048), dim3(256), 0, stream>>>(qkv, kvT, ksp, qkv + 4096);
  // final: out = attn @ o_w^T + o_b, A = v-columns of qkv (astr=QSTR), fp32 out
  gemm256<0, 0><<<dim3(8 * 64), dim3(512), 0, stream>>>(
      qkv + 4096, owb, owb, owb, ob, ob, ob, d_out, 8, QSTR, HIDC);
}

// Round 7
// 774.411 us; speedup vs baseline: 2.9920x; 1.0121x over previous
//
#include <hip/hip_runtime.h>
#include <hip/hip_bf16.h>

#define HIDC 2048
#define NHEADS 16
#define HDIM 128
#define NB 4
#define NS 4096
#define NROWS (NB*NS)
#define QSTR 6144
#define EPSV 1e-6f

typedef __attribute__((ext_vector_type(8))) short s16x8;
typedef __attribute__((ext_vector_type(4))) float f32x4;
typedef __attribute__((ext_vector_type(8))) unsigned short u16x8;

static __device__ __forceinline__ unsigned short f2b(float f) {
  unsigned int u = __float_as_uint(f);
  u += 0x7fffu + ((u >> 16) & 1u);
  return (unsigned short)(u >> 16);
}
static __device__ __forceinline__ float b2f(unsigned short h) {
  return __uint_as_float(((unsigned int)h) << 16);
}

static __device__ __forceinline__ void gload_lds16(const unsigned short* g, unsigned short* l) {
  __builtin_amdgcn_global_load_lds(
      (const __attribute__((address_space(1))) void*)g,
      (__attribute__((address_space(3))) void*)l, 16, 0, 0);
}

// fp32 -> bf16 conversion for hs (16384 blocks) + 4 weights (2048 blocks each)
__global__ __launch_bounds__(256) void convert_all(
    const float* __restrict__ hs, const float* __restrict__ qw,
    const float* __restrict__ kw, const float* __restrict__ vw,
    const float* __restrict__ ow,
    unsigned short* __restrict__ hsb, unsigned short* __restrict__ qwb,
    unsigned short* __restrict__ kwb, unsigned short* __restrict__ vwb,
    unsigned short* __restrict__ owb)
{
  int bid = blockIdx.x;
  const float* src; unsigned short* dst; size_t base;
  if (bid < 16384) { src = hs; dst = hsb; base = (size_t)bid << 11; }
  else {
    int t = bid - 16384; int wsel = t >> 11; int wb = t & 2047;
    src = wsel == 0 ? qw : wsel == 1 ? kw : wsel == 2 ? vw : ow;
    dst = wsel == 0 ? qwb : wsel == 1 ? kwb : wsel == 2 ? vwb : owb;
    base = (size_t)wb << 11;
  }
  size_t i = base + ((size_t)threadIdx.x << 3);
  float4 a = *(const float4*)(src + i);
  float4 b = *(const float4*)(src + i + 4);
  u16x8 o;
  o[0] = f2b(a.x); o[1] = f2b(a.y); o[2] = f2b(a.z); o[3] = f2b(a.w);
  o[4] = f2b(b.x); o[5] = f2b(b.y); o[6] = f2b(b.z); o[7] = f2b(b.w);
  *(u16x8*)(dst + i) = o;
}

// 256x256-tile bf16 GEMM, 8 waves (2Mx4N), BK=32, ring-of-4 LDS slots,
// 3-deep vmem prefetch + cross-window ds_read pipelining. RACE-FIXED layout:
//   W1(s): issue ahi(s) reads | stage A(s+3) | bar | MFMA alo(s)xb(s) |
//          GATE vmcnt(6) | bar      <- every wave gates BEFORE the barrier
//   W2(s): prefetch b(s+1),alo(s+1) (safe: post-gate+barrier) | stage B(s+3) |
//          bar | MFMA ahi(s)xb(s) | bar
// ds_reads drain during the adjacent MFMA clusters (counted lgkm, no lgkmcnt(0)).
// XOR-swizzled LDS (0 conflicts). K fixed = 2048 (64 steps).
template<int QKV, int OUT_BF16>
__global__ __launch_bounds__(512, 2) void gemm256(
    const unsigned short* __restrict__ A,
    const unsigned short* __restrict__ B0,
    const unsigned short* __restrict__ B1,
    const unsigned short* __restrict__ B2,
    const float* __restrict__ bias0,
    const float* __restrict__ bias1,
    const float* __restrict__ bias2,
    void* __restrict__ Cp,
    int ntile, int astr, int ostr)
{
  __shared__ unsigned short lds[65536];   // 128 KiB: [slot:4][op:2][8192]
  const int tid = threadIdx.x;
  const int lane = tid & 63, wid = tid >> 6;
  const int wr = wid >> 2, wc = wid & 3;
  const int l15 = lane & 15, l4 = lane >> 4;

  // bijective XCD swizzle (grid % 8 == 0) + L2 chunking: 4 bm x all bn
  const int cpx = (int)gridDim.x >> 3;
  const int bidx = (int)blockIdx.x;
  const int wg = (bidx & 7) * cpx + (bidx >> 3);
  const int csz = ntile << 2;
  const int chunk = wg / csz;
  const int t = wg % csz;
  const int bm = ((chunk << 2) + (t & 3)) << 8;
  const int bn = (t >> 2) << 8;

  const unsigned short* Bp = B0;
  const float* bias = bias0;
  bool act = false;
  int bnw = bn;
  if (QKV) {
    int seg = bn >> 11;
    Bp = seg == 0 ? B0 : (seg == 1 ? B1 : B2);
    bias = seg == 0 ? bias0 : (seg == 1 ? bias1 : bias2);
    act = seg < 2;
    bnw = bn & 2047;
  }

  // staging: wave stages chunks {2*wid, 2*wid+1} of A and B. chunk = 16 rows
  // x 32 cols (1024B). source col inverse-swizzled (linear LDS write +
  // swizzled read = consistent involution).
  const int c0 = wid << 1;
  const int srow = lane >> 2;
  const int scol = (((lane & 3) ^ ((srow >> 1) & 3)) << 3);
  const unsigned short* Asrc0 = A + (size_t)(bm + (c0 << 4) + srow) * astr + scol;
  const unsigned short* Asrc1 = Asrc0 + (size_t)16 * astr;
  const unsigned short* Bsrc0 = Bp + (size_t)(bnw + (c0 << 4) + srow) * HIDC + scol;
  const unsigned short* Bsrc1 = Bsrc0 + (size_t)16 * HIDC;
  const int adst = c0 << 9;               // ushort idx within op region

  // fragment read offsets (swizzled): row*32 + ((l4 ^ ((row>>1)&3))<<3)
  const int xa = ((l4 ^ ((l15 >> 1) & 3)) << 3);
  const int abase = ((wr << 7) + l15) * 32 + xa;
  const int bbase = 8192 + ((wc << 6) + l15) * 32 + xa;

  f32x4 acc[8][4] = {};
  s16x8 bfr[2][4];   // B frags, double-buffered across steps (compile-time parity)
  s16x8 alo[2][4];   // A frags mf0-3, double-buffered
  s16x8 ahi[4];      // A frags mf4-7, single set (read W1, used phase B)

#define STAGE_A(s_) { const int sl_ = ((s_) & 3) << 14; const int kt_ = (s_) << 5; \
    gload_lds16(Asrc0 + kt_, &lds[sl_ + adst]); \
    gload_lds16(Asrc1 + kt_, &lds[sl_ + adst + 512]); }
#define STAGE_B(s_) { const int sl_ = ((s_) & 3) << 14; const int kt_ = (s_) << 5; \
    gload_lds16(Bsrc0 + kt_, &lds[sl_ + 8192 + adst]); \
    gload_lds16(Bsrc1 + kt_, &lds[sl_ + 8192 + adst + 512]); }

#define MM4(ai_, r_, P_) { \
    acc[r_][0] = __builtin_amdgcn_mfma_f32_16x16x32_bf16(ai_, bfr[P_][0], acc[r_][0], 0, 0, 0); \
    acc[r_][1] = __builtin_amdgcn_mfma_f32_16x16x32_bf16(ai_, bfr[P_][1], acc[r_][1], 0, 0, 0); \
    acc[r_][2] = __builtin_amdgcn_mfma_f32_16x16x32_bf16(ai_, bfr[P_][2], acc[r_][2], 0, 0, 0); \
    acc[r_][3] = __builtin_amdgcn_mfma_f32_16x16x32_bf16(ai_, bfr[P_][3], acc[r_][3], 0, 0, 0); }

#define DO_STEP(s_, P_, STG, GATE, NEXT) { \
    const int sl = ((s_) & 3) << 14; \
    /* ---- W1: issue ahi(s); stage A(s+3); MFMA alo(s) x b(s); GATE; bar ---- */ \
    ahi[0] = *(const s16x8*)&lds[sl + abase + 2048]; \
    ahi[1] = *(const s16x8*)&lds[sl + abase + 2560]; \
    ahi[2] = *(const s16x8*)&lds[sl + abase + 3072]; \
    ahi[3] = *(const s16x8*)&lds[sl + abase + 3584]; \
    if (STG) STAGE_A((s_) + 3); \
    __builtin_amdgcn_sched_barrier(0); \
    __builtin_amdgcn_s_barrier(); \
    __builtin_amdgcn_s_setprio(1); \
    MM4(alo[P_][0], 0, P_) MM4(alo[P_][1], 1, P_) \
    MM4(alo[P_][2], 2, P_) MM4(alo[P_][3], 3, P_) \
    __builtin_amdgcn_s_setprio(0); \
    if ((GATE) == 6)      { asm volatile("s_waitcnt vmcnt(6)" ::: "memory"); } \
    else if ((GATE) == 4) { asm volatile("s_waitcnt vmcnt(4)" ::: "memory"); } \
    else if ((GATE) == 0) { asm volatile("s_waitcnt vmcnt(0)" ::: "memory"); } \
    __builtin_amdgcn_s_barrier(); \
    /* ---- W2: prefetch slot s+1 (post-gate+bar = safe); stage B(s+3); MFMA ahi x b ---- */ \
    if (NEXT) { \
      const int sln = (((s_) + 1) & 3) << 14; \
      bfr[1-(P_)][0] = *(const s16x8*)&lds[sln + bbase]; \
      bfr[1-(P_)][1] = *(const s16x8*)&lds[sln + bbase + 512]; \
      bfr[1-(P_)][2] = *(const s16x8*)&lds[sln + bbase + 1024]; \
      bfr[1-(P_)][3] = *(const s16x8*)&lds[sln + bbase + 1536]; \
      alo[1-(P_)][0] = *(const s16x8*)&lds[sln + abase]; \
      alo[1-(P_)][1] = *(const s16x8*)&lds[sln + abase + 512]; \
      alo[1-(P_)][2] = *(const s16x8*)&lds[sln + abase + 1024]; \
      alo[1-(P_)][3] = *(const s16x8*)&lds[sln + abase + 1536]; \
    } \
    if (STG) STAGE_B((s_) + 3); \
    __builtin_amdgcn_sched_barrier(0); \
    __builtin_amdgcn_s_barrier(); \
    __builtin_amdgcn_s_setprio(1); \
    MM4(ahi[0], 4, P_) MM4(ahi[1], 5, P_) \
    MM4(ahi[2], 6, P_) MM4(ahi[3], 7, P_) \
    __builtin_amdgcn_s_setprio(0); \
    __builtin_amdgcn_s_barrier(); \
  }

  // prologue: stage slots 0,1,2; gate A0,B0 resident; pre-read b(0), alo(0)
  STAGE_A(0); STAGE_B(0);
  STAGE_A(1); STAGE_B(1);
  STAGE_A(2); STAGE_B(2);
  asm volatile("s_waitcnt vmcnt(8)" ::: "memory");
  __builtin_amdgcn_s_barrier();
  bfr[0][0] = *(const s16x8*)&lds[bbase];
  bfr[0][1] = *(const s16x8*)&lds[bbase + 512];
  bfr[0][2] = *(const s16x8*)&lds[bbase + 1024];
  bfr[0][3] = *(const s16x8*)&lds[bbase + 1536];
  alo[0][0] = *(const s16x8*)&lds[abase];
  alo[0][1] = *(const s16x8*)&lds[abase + 512];
  alo[0][2] = *(const s16x8*)&lds[abase + 1024];
  alo[0][3] = *(const s16x8*)&lds[abase + 1536];

  for (int s = 0; s < 60; s += 2) {
    DO_STEP(s,     0, 1, 6, 1)
    DO_STEP(s + 1, 1, 1, 6, 1)
  }
  DO_STEP(60, 0, 1, 6, 1)
  DO_STEP(61, 1, 0, 4, 1)
  DO_STEP(62, 0, 0, 0, 1)
  DO_STEP(63, 1, 0, -1, 0)

#undef DO_STEP
#undef MM4
#undef STAGE_A
#undef STAGE_B

  #pragma unroll
  for (int nf = 0; nf < 4; ++nf) {
    const int colw = (wc << 6) + (nf << 4) + l15;
    const float bv = bias[bnw + colw];
    #pragma unroll
    for (int mf = 0; mf < 8; ++mf) {
      #pragma unroll
      for (int r = 0; r < 4; ++r) {
        const int row = bm + (wr << 7) + (mf << 4) + (l4 << 2) + r;
        float v = acc[mf][nf][r] + bv;
        if (QKV) { if (act) v = (v > 0.f) ? (v + 1.f) : __expf(v); }
        const size_t off = (size_t)row * ostr + bn + colw;
        if (OUT_BF16) ((unsigned short*)Cp)[off] = f2b(v);
        else          ((float*)Cp)[off] = v;
      }
    }
  }
}

// kv partials over 8 S-chunks (deterministic, no atomics).
__global__ __launch_bounds__(256) void kv_partial(
    const unsigned short* __restrict__ kp, const unsigned short* __restrict__ vv,
    float* __restrict__ kvp, float* __restrict__ ksp)
{
  const int bh = blockIdx.x >> 3;
  const int chunk = blockIdx.x & 7;
  const int b = bh >> 4, h = bh & 15;
  const int tid = threadIdx.x;
  const int td = tid >> 4, te = tid & 15;

  __shared__ float kpl[32][128];
  __shared__ float vl[32][132];

  float acc[8][8] = {};
  float ks[8] = {};

  const size_t rowbase = (size_t)b * NS * QSTR + (size_t)h * HDIM;
  const int s0 = chunk * 512;

  for (int st = 0; st < 512; st += 32) {
    __syncthreads();
    #pragma unroll
    for (int i = 0; i < 2; ++i) {
      int idx = tid + (i << 8);
      int row = idx >> 4, q = idx & 15;
      size_t g = rowbase + (size_t)(s0 + st + row) * QSTR + (q << 3);
      u16x8 k8 = *(const u16x8*)(kp + g);
      u16x8 v8 = *(const u16x8*)(vv + g);
      float tk[8], tv[8];
      #pragma unroll
      for (int j = 0; j < 8; ++j) { tk[j] = b2f(k8[j]); tv[j] = b2f(v8[j]); }
      *(float4*)&kpl[row][(q << 3)]     = make_float4(tk[0], tk[1], tk[2], tk[3]);
      *(float4*)&kpl[row][(q << 3) + 4] = make_float4(tk[4], tk[5], tk[6], tk[7]);
      *(float4*)&vl[row][(q << 3)]      = make_float4(tv[0], tv[1], tv[2], tv[3]);
      *(float4*)&vl[row][(q << 3) + 4]  = make_float4(tv[4], tv[5], tv[6], tv[7]);
    }
    __syncthreads();
    #pragma unroll 4
    for (int s = 0; s < 32; ++s) {
      float kd[8], ve[8];
      *(float4*)&kd[0] = *(const float4*)&kpl[s][td << 3];
      *(float4*)&kd[4] = *(const float4*)&kpl[s][(td << 3) + 4];
      *(float4*)&ve[0] = *(const float4*)&vl[s][te << 3];
      *(float4*)&ve[4] = *(const float4*)&vl[s][(te << 3) + 4];
      if (te == 0) {
        #pragma unroll
        for (int i = 0; i < 8; ++i) ks[i] += kd[i];
      }
      #pragma unroll
      for (int i = 0; i < 8; ++i)
        #pragma unroll
        for (int j = 0; j < 8; ++j)
          acc[i][j] += kd[i] * ve[j];
    }
  }

  float* outp = kvp + ((size_t)(chunk * 64 + bh) << 14);
  #pragma unroll
  for (int j = 0; j < 8; ++j) {
    int e = (te << 3) + j;
    float r0[8];
    #pragma unroll
    for (int i = 0; i < 8; ++i) r0[i] = acc[i][j];
    *(float4*)&outp[(size_t)e * HDIM + (td << 3)]     = *(float4*)&r0[0];
    *(float4*)&outp[(size_t)e * HDIM + (td << 3) + 4] = *(float4*)&r0[4];
  }
  if (te == 0) {
    float* kso = ksp + ((size_t)(chunk * 64 + bh) << 7) + (td << 3);
    #pragma unroll
    for (int i = 0; i < 8; ++i) kso[i] = ks[i];
  }
}

__global__ __launch_bounds__(256) void kv_reduce(
    const float* __restrict__ kvp, float* __restrict__ kvT)
{
  int i = blockIdx.x * 256 + threadIdx.x;
  float s = 0.f;
  #pragma unroll
  for (int c = 0; c < 8; ++c) s += kvp[(size_t)c * (64 * 16384) + i];
  kvT[i] = s;
}

// attn[s,e] = (qp[s,:] . kvT[e,:]) / (z[s]+eps); qp = q cols of qkv, out -> v cols.
__global__ __launch_bounds__(256) void attn_ker(
    const unsigned short* __restrict__ qp, const float* __restrict__ kvT,
    const float* __restrict__ ksp, unsigned short* __restrict__ attn)
{
  const int bh = blockIdx.x >> 5, stile = blockIdx.x & 31;
  const int b = bh >> 4, h = bh & 15;
  const int tid = threadIdx.x;
  const int lane = tid & 63, w = tid >> 6;
  const int l15 = lane & 15, l4 = lane >> 4;

  __shared__ unsigned short Qs[128][136];
  __shared__ unsigned short Ks[128][136];
  __shared__ float ksl[128];
  __shared__ float zs[128];

  const size_t qbase = ((size_t)b * NS + (size_t)stile * 128) * QSTR + (size_t)h * HDIM;

  #pragma unroll
  for (int i = 0; i < 8; ++i) {
    int idx = tid + (i << 8);
    int row = idx >> 4, q = idx & 15;
    u16x8 v8 = *(const u16x8*)(qp + qbase + (size_t)row * QSTR + (q << 3));
    *(u16x8*)&Qs[row][q << 3] = v8;
  }
  const float* kvb = kvT + ((size_t)bh << 14);
  #pragma unroll
  for (int i = 0; i < 16; ++i) {
    int idx = tid + (i << 8);
    int row = idx >> 5, q = idx & 31;
    float4 v4 = *(const float4*)(kvb + (size_t)row * HDIM + (q << 2));
    ushort4 w4; w4.x = f2b(v4.x); w4.y = f2b(v4.y); w4.z = f2b(v4.z); w4.w = f2b(v4.w);
    *(ushort4*)&Ks[row][q << 2] = w4;
  }
  if (tid < 128) {
    float s = 0.f;
    #pragma unroll
    for (int c = 0; c < 8; ++c) s += ksp[((size_t)(c * 64 + bh) << 7) + tid];
    ksl[tid] = s;
  }
  __syncthreads();
  if (tid < 128) {
    float z = 0.f;
    #pragma unroll
    for (int dq = 0; dq < 16; ++dq) {
      u16x8 qv = *(const u16x8*)&Qs[tid][dq << 3];
      #pragma unroll
      for (int j = 0; j < 8; ++j) z += b2f(qv[j]) * ksl[(dq << 3) + j];
    }
    zs[tid] = 1.f / (z + EPSV);
  }
  __syncthreads();

  f32x4 acc[2][8] = {};
  #pragma unroll
  for (int kk = 0; kk < 4; ++kk) {
    s16x8 a[2], bb[8];
    #pragma unroll
    for (int mf = 0; mf < 2; ++mf)
      a[mf] = *(const s16x8*)&Qs[(w << 5) + (mf << 4) + l15][(kk << 5) + (l4 << 3)];
    #pragma unroll
    for (int nf = 0; nf < 8; ++nf)
      bb[nf] = *(const s16x8*)&Ks[(nf << 4) + l15][(kk << 5) + (l4 << 3)];
    #pragma unroll
    for (int mf = 0; mf < 2; ++mf)
      #pragma unroll
      for (int nf = 0; nf < 8; ++nf)
        acc[mf][nf] = __builtin_amdgcn_mfma_f32_16x16x32_bf16(a[mf], bb[nf], acc[mf][nf], 0, 0, 0);
  }

  #pragma unroll
  for (int mf = 0; mf < 2; ++mf) {
    #pragma unroll
    for (int r = 0; r < 4; ++r) {
      const int rl = (w << 5) + (mf << 4) + (l4 << 2) + r;
      const float zi = zs[rl];
      #pragma unroll
      for (int nf = 0; nf < 8; ++nf) {
        const int e = (nf << 4) + l15;
        attn[qbase + (size_t)rl * QSTR + e] = f2b(acc[mf][nf][r] * zi);
      }
    }
  }
}

extern "C" void kernel_launch(void* const* d_in, const int* in_sizes, int n_in,
                              void* d_out, int out_size, void* d_ws, size_t ws_size,
                              hipStream_t stream) {
  const float* hs = (const float*)d_in[0];
  const float* qw = (const float*)d_in[1];
  const float* qb = (const float*)d_in[2];
  const float* kw = (const float*)d_in[3];
  const float* kb = (const float*)d_in[4];
  const float* vw = (const float*)d_in[5];
  const float* vb = (const float*)d_in[6];
  const float* ow = (const float*)d_in[7];
  const float* ob = (const float*)d_in[8];

  char* w = (char*)d_ws;
  unsigned short* hsb = (unsigned short*)(w);                  // 64 MiB (dead after QKV gemm)
  unsigned short* qwb = (unsigned short*)(w + 67108864);       // 8 MiB each
  unsigned short* kwb = (unsigned short*)(w + 75497472);
  unsigned short* vwb = (unsigned short*)(w + 83886080);
  unsigned short* owb = (unsigned short*)(w + 92274688);
  unsigned short* qkv = (unsigned short*)(w + 100663296);      // 192 MiB, row stride 6144
  // aliases over the dead hsb region:
  float* kvp = (float*)(w);                                    // 32 MiB
  float* ksp = (float*)(w + 33554432);                         // 256 KiB
  float* kvT = (float*)(w + 33816576);                         // 4 MiB

  convert_all<<<dim3(24576), dim3(256), 0, stream>>>(hs, qw, kw, vw, ow, hsb, qwb, kwb, vwb, owb);
  // QKV fused: M=16384, N=6144 (q|k|v columns), elu+1 on q,k
  gemm256<1, 1><<<dim3(24 * 64), dim3(512), 0, stream>>>(
      hsb, qwb, kwb, vwb, qb, kb, vb, qkv, 24, HIDC, QSTR);
  kv_partial<<<dim3(512), dim3(256), 0, stream>>>(qkv + 2048, qkv + 4096, kvp, ksp);
  kv_reduce<<<dim3(4096), dim3(256), 0, stream>>>(kvp, kvT);
  attn_ker<<<dim3(2048), dim3(256), 0, stream>>>(qkv, kvT, ksp, qkv + 4096);
  // final: out = attn @ o_w^T + o_b, A = v-columns of qkv (astr=QSTR), fp32 out
  gemm256<0, 0><<<dim3(8 * 64), dim3(512), 0, stream>>>(
      qkv + 4096, owb, owb, owb, ob, ob, ob, d_out, 8, QSTR, HIDC);
}

// Round 8
// 764.009 us; speedup vs baseline: 3.0327x; 1.0136x over previous
//
#include <hip/hip_runtime.h>
#include <hip/hip_bf16.h>

#define HIDC 2048
#define NHEADS 16
#define HDIM 128
#define NB 4
#define NS 4096
#define NROWS (NB*NS)
#define QSTR 6144
#define EPSV 1e-6f

typedef __attribute__((ext_vector_type(8))) short s16x8;
typedef __attribute__((ext_vector_type(4))) float f32x4;
typedef __attribute__((ext_vector_type(8))) unsigned short u16x8;

static __device__ __forceinline__ unsigned short f2b(float f) {
  unsigned int u = __float_as_uint(f);
  u += 0x7fffu + ((u >> 16) & 1u);
  return (unsigned short)(u >> 16);
}
static __device__ __forceinline__ float b2f(unsigned short h) {
  return __uint_as_float(((unsigned int)h) << 16);
}

static __device__ __forceinline__ void gload_lds16(const unsigned short* g, unsigned short* l) {
  __builtin_amdgcn_global_load_lds(
      (const __attribute__((address_space(1))) void*)g,
      (__attribute__((address_space(3))) void*)l, 16, 0, 0);
}

// fp32 -> bf16 conversion for hs (16384 blocks) + 4 weights (2048 blocks each)
__global__ __launch_bounds__(256) void convert_all(
    const float* __restrict__ hs, const float* __restrict__ qw,
    const float* __restrict__ kw, const float* __restrict__ vw,
    const float* __restrict__ ow,
    unsigned short* __restrict__ hsb, unsigned short* __restrict__ qwb,
    unsigned short* __restrict__ kwb, unsigned short* __restrict__ vwb,
    unsigned short* __restrict__ owb)
{
  int bid = blockIdx.x;
  const float* src; unsigned short* dst; size_t base;
  if (bid < 16384) { src = hs; dst = hsb; base = (size_t)bid << 11; }
  else {
    int t = bid - 16384; int wsel = t >> 11; int wb = t & 2047;
    src = wsel == 0 ? qw : wsel == 1 ? kw : wsel == 2 ? vw : ow;
    dst = wsel == 0 ? qwb : wsel == 1 ? kwb : wsel == 2 ? vwb : owb;
    base = (size_t)wb << 11;
  }
  size_t i = base + ((size_t)threadIdx.x << 3);
  float4 a = *(const float4*)(src + i);
  float4 b = *(const float4*)(src + i + 4);
  u16x8 o;
  o[0] = f2b(a.x); o[1] = f2b(a.y); o[2] = f2b(a.z); o[3] = f2b(a.w);
  o[4] = f2b(b.x); o[5] = f2b(b.y); o[6] = f2b(b.z); o[7] = f2b(b.w);
  *(u16x8*)(dst + i) = o;
}

// 256x256-tile bf16 GEMM, 8 waves (2Mx4N), BK=32, ring-of-4 LDS slots,
// 3-deep vmem prefetch, cross-window ds_read pipelining, 2 barriers/step:
//   W1(s): issue ahi(s) | stage A(s+3) | MFMA alo(s)xb(s) | GATE vmcnt | bar
//   W2(s): prefetch b(s+1),alo(s+1) (post-gate+bar = safe) | stage B(s+3) |
//          MFMA ahi(s)xb(s) [lgkm-counted wait on ahi] | bar
// Correctness audit: stage-writes to slot s-1 are safe via end-of-step barrier
// (slot s-1's last reads lgkm-drain before their consumers' MFMA, pre-barrier);
// slot s+1 prefetch reads are safe via gate+bar. XOR-swizzled LDS (0 conflicts).
template<int QKV, int OUT_BF16>
__global__ __launch_bounds__(512, 2) void gemm256(
    const unsigned short* __restrict__ A,
    const unsigned short* __restrict__ B0,
    const unsigned short* __restrict__ B1,
    const unsigned short* __restrict__ B2,
    const float* __restrict__ bias0,
    const float* __restrict__ bias1,
    const float* __restrict__ bias2,
    void* __restrict__ Cp,
    int ntile, int astr, int ostr)
{
  __shared__ unsigned short lds[65536];   // 128 KiB: [slot:4][op:2][8192]
  const int tid = threadIdx.x;
  const int lane = tid & 63, wid = tid >> 6;
  const int wr = wid >> 2, wc = wid & 3;
  const int l15 = lane & 15, l4 = lane >> 4;

  // bijective XCD swizzle (grid % 8 == 0) + L2 chunking: 4 bm x all bn
  const int cpx = (int)gridDim.x >> 3;
  const int bidx = (int)blockIdx.x;
  const int wg = (bidx & 7) * cpx + (bidx >> 3);
  const int csz = ntile << 2;
  const int chunk = wg / csz;
  const int t = wg % csz;
  const int bm = ((chunk << 2) + (t & 3)) << 8;
  const int bn = (t >> 2) << 8;

  const unsigned short* Bp = B0;
  const float* bias = bias0;
  bool act = false;
  int bnw = bn;
  if (QKV) {
    int seg = bn >> 11;
    Bp = seg == 0 ? B0 : (seg == 1 ? B1 : B2);
    bias = seg == 0 ? bias0 : (seg == 1 ? bias1 : bias2);
    act = seg < 2;
    bnw = bn & 2047;
  }

  // staging: wave stages chunks {2*wid, 2*wid+1} of A and B. chunk = 16 rows
  // x 32 cols (1024B). source col inverse-swizzled (linear LDS write +
  // swizzled read = consistent involution).
  const int c0 = wid << 1;
  const int srow = lane >> 2;
  const int scol = (((lane & 3) ^ ((srow >> 1) & 3)) << 3);
  const unsigned short* Asrc0 = A + (size_t)(bm + (c0 << 4) + srow) * astr + scol;
  const unsigned short* Asrc1 = Asrc0 + (size_t)16 * astr;
  const unsigned short* Bsrc0 = Bp + (size_t)(bnw + (c0 << 4) + srow) * HIDC + scol;
  const unsigned short* Bsrc1 = Bsrc0 + (size_t)16 * HIDC;
  const int adst = c0 << 9;               // ushort idx within op region

  // fragment read offsets (swizzled): row*32 + ((l4 ^ ((row>>1)&3))<<3)
  const int xa = ((l4 ^ ((l15 >> 1) & 3)) << 3);
  const int abase = ((wr << 7) + l15) * 32 + xa;
  const int bbase = 8192 + ((wc << 6) + l15) * 32 + xa;

  f32x4 acc[8][4] = {};
  s16x8 bfr[2][4];   // B frags, double-buffered across steps (compile-time parity)
  s16x8 alo[2][4];   // A frags mf0-3, double-buffered
  s16x8 ahi[4];      // A frags mf4-7, single set (read W1, used phase B)

#define STAGE_A(s_) { const int sl_ = ((s_) & 3) << 14; const int kt_ = (s_) << 5; \
    gload_lds16(Asrc0 + kt_, &lds[sl_ + adst]); \
    gload_lds16(Asrc1 + kt_, &lds[sl_ + adst + 512]); }
#define STAGE_B(s_) { const int sl_ = ((s_) & 3) << 14; const int kt_ = (s_) << 5; \
    gload_lds16(Bsrc0 + kt_, &lds[sl_ + 8192 + adst]); \
    gload_lds16(Bsrc1 + kt_, &lds[sl_ + 8192 + adst + 512]); }

#define MM4(ai_, r_, P_) { \
    acc[r_][0] = __builtin_amdgcn_mfma_f32_16x16x32_bf16(ai_, bfr[P_][0], acc[r_][0], 0, 0, 0); \
    acc[r_][1] = __builtin_amdgcn_mfma_f32_16x16x32_bf16(ai_, bfr[P_][1], acc[r_][1], 0, 0, 0); \
    acc[r_][2] = __builtin_amdgcn_mfma_f32_16x16x32_bf16(ai_, bfr[P_][2], acc[r_][2], 0, 0, 0); \
    acc[r_][3] = __builtin_amdgcn_mfma_f32_16x16x32_bf16(ai_, bfr[P_][3], acc[r_][3], 0, 0, 0); }

#define DO_STEP(s_, P_, STG, GATE, NEXT) { \
    const int sl = ((s_) & 3) << 14; \
    /* ---- W1: issue ahi(s); stage A(s+3); MFMA alo(s) x b(s); GATE; bar ---- */ \
    ahi[0] = *(const s16x8*)&lds[sl + abase + 2048]; \
    ahi[1] = *(const s16x8*)&lds[sl + abase + 2560]; \
    ahi[2] = *(const s16x8*)&lds[sl + abase + 3072]; \
    ahi[3] = *(const s16x8*)&lds[sl + abase + 3584]; \
    if (STG) STAGE_A((s_) + 3); \
    __builtin_amdgcn_sched_barrier(0); \
    __builtin_amdgcn_s_setprio(1); \
    MM4(alo[P_][0], 0, P_) MM4(alo[P_][1], 1, P_) \
    MM4(alo[P_][2], 2, P_) MM4(alo[P_][3], 3, P_) \
    __builtin_amdgcn_s_setprio(0); \
    if ((GATE) == 6)      { asm volatile("s_waitcnt vmcnt(6)" ::: "memory"); } \
    else if ((GATE) == 4) { asm volatile("s_waitcnt vmcnt(4)" ::: "memory"); } \
    else if ((GATE) == 0) { asm volatile("s_waitcnt vmcnt(0)" ::: "memory"); } \
    __builtin_amdgcn_s_barrier(); \
    /* ---- W2: prefetch slot s+1 (post-gate+bar = safe); stage B(s+3); MFMA ahi x b ---- */ \
    if (NEXT) { \
      const int sln = (((s_) + 1) & 3) << 14; \
      bfr[1-(P_)][0] = *(const s16x8*)&lds[sln + bbase]; \
      bfr[1-(P_)][1] = *(const s16x8*)&lds[sln + bbase + 512]; \
      bfr[1-(P_)][2] = *(const s16x8*)&lds[sln + bbase + 1024]; \
      bfr[1-(P_)][3] = *(const s16x8*)&lds[sln + bbase + 1536]; \
      alo[1-(P_)][0] = *(const s16x8*)&lds[sln + abase]; \
      alo[1-(P_)][1] = *(const s16x8*)&lds[sln + abase + 512]; \
      alo[1-(P_)][2] = *(const s16x8*)&lds[sln + abase + 1024]; \
      alo[1-(P_)][3] = *(const s16x8*)&lds[sln + abase + 1536]; \
    } \
    if (STG) STAGE_B((s_) + 3); \
    __builtin_amdgcn_sched_barrier(0); \
    __builtin_amdgcn_s_setprio(1); \
    MM4(ahi[0], 4, P_) MM4(ahi[1], 5, P_) \
    MM4(ahi[2], 6, P_) MM4(ahi[3], 7, P_) \
    __builtin_amdgcn_s_setprio(0); \
    __builtin_amdgcn_s_barrier(); \
  }

  // prologue: stage slots 0,1,2; gate A0,B0 resident; pre-read b(0), alo(0)
  STAGE_A(0); STAGE_B(0);
  STAGE_A(1); STAGE_B(1);
  STAGE_A(2); STAGE_B(2);
  asm volatile("s_waitcnt vmcnt(8)" ::: "memory");
  __builtin_amdgcn_s_barrier();
  bfr[0][0] = *(const s16x8*)&lds[bbase];
  bfr[0][1] = *(const s16x8*)&lds[bbase + 512];
  bfr[0][2] = *(const s16x8*)&lds[bbase + 1024];
  bfr[0][3] = *(const s16x8*)&lds[bbase + 1536];
  alo[0][0] = *(const s16x8*)&lds[abase];
  alo[0][1] = *(const s16x8*)&lds[abase + 512];
  alo[0][2] = *(const s16x8*)&lds[abase + 1024];
  alo[0][3] = *(const s16x8*)&lds[abase + 1536];

  for (int s = 0; s < 60; s += 2) {
    DO_STEP(s,     0, 1, 6, 1)
    DO_STEP(s + 1, 1, 1, 6, 1)
  }
  DO_STEP(60, 0, 1, 6, 1)
  DO_STEP(61, 1, 0, 4, 1)
  DO_STEP(62, 0, 0, 0, 1)
  DO_STEP(63, 1, 0, -1, 0)

#undef DO_STEP
#undef MM4
#undef STAGE_A
#undef STAGE_B

  #pragma unroll
  for (int nf = 0; nf < 4; ++nf) {
    const int colw = (wc << 6) + (nf << 4) + l15;
    const float bv = bias[bnw + colw];
    #pragma unroll
    for (int mf = 0; mf < 8; ++mf) {
      #pragma unroll
      for (int r = 0; r < 4; ++r) {
        const int row = bm + (wr << 7) + (mf << 4) + (l4 << 2) + r;
        float v = acc[mf][nf][r] + bv;
        if (QKV) { if (act) v = (v > 0.f) ? (v + 1.f) : __expf(v); }
        const size_t off = (size_t)row * ostr + bn + colw;
        if (OUT_BF16) ((unsigned short*)Cp)[off] = f2b(v);
        else          ((float*)Cp)[off] = v;
      }
    }
  }
}

// kv partials over 16 S-chunks (deterministic, no atomics). 1024 blocks -> 4/CU.
__global__ __launch_bounds__(256) void kv_partial(
    const unsigned short* __restrict__ kp, const unsigned short* __restrict__ vv,
    float* __restrict__ kvp, float* __restrict__ ksp)
{
  const int bh = blockIdx.x >> 4;
  const int chunk = blockIdx.x & 15;
  const int b = bh >> 4, h = bh & 15;
  const int tid = threadIdx.x;
  const int td = tid >> 4, te = tid & 15;

  __shared__ float kpl[32][128];
  __shared__ float vl[32][132];

  float acc[8][8] = {};
  float ks[8] = {};

  const size_t rowbase = (size_t)b * NS * QSTR + (size_t)h * HDIM;
  const int s0 = chunk * 256;

  for (int st = 0; st < 256; st += 32) {
    __syncthreads();
    #pragma unroll
    for (int i = 0; i < 2; ++i) {
      int idx = tid + (i << 8);
      int row = idx >> 4, q = idx & 15;
      size_t g = rowbase + (size_t)(s0 + st + row) * QSTR + (q << 3);
      u16x8 k8 = *(const u16x8*)(kp + g);
      u16x8 v8 = *(const u16x8*)(vv + g);
      float tk[8], tv[8];
      #pragma unroll
      for (int j = 0; j < 8; ++j) { tk[j] = b2f(k8[j]); tv[j] = b2f(v8[j]); }
      *(float4*)&kpl[row][(q << 3)]     = make_float4(tk[0], tk[1], tk[2], tk[3]);
      *(float4*)&kpl[row][(q << 3) + 4] = make_float4(tk[4], tk[5], tk[6], tk[7]);
      *(float4*)&vl[row][(q << 3)]      = make_float4(tv[0], tv[1], tv[2], tv[3]);
      *(float4*)&vl[row][(q << 3) + 4]  = make_float4(tv[4], tv[5], tv[6], tv[7]);
    }
    __syncthreads();
    #pragma unroll 4
    for (int s = 0; s < 32; ++s) {
      float kd[8], ve[8];
      *(float4*)&kd[0] = *(const float4*)&kpl[s][td << 3];
      *(float4*)&kd[4] = *(const float4*)&kpl[s][(td << 3) + 4];
      *(float4*)&ve[0] = *(const float4*)&vl[s][te << 3];
      *(float4*)&ve[4] = *(const float4*)&vl[s][(te << 3) + 4];
      if (te == 0) {
        #pragma unroll
        for (int i = 0; i < 8; ++i) ks[i] += kd[i];
      }
      #pragma unroll
      for (int i = 0; i < 8; ++i)
        #pragma unroll
        for (int j = 0; j < 8; ++j)
          acc[i][j] += kd[i] * ve[j];
    }
  }

  float* outp = kvp + ((size_t)(chunk * 64 + bh) << 14);
  #pragma unroll
  for (int j = 0; j < 8; ++j) {
    int e = (te << 3) + j;
    float r0[8];
    #pragma unroll
    for (int i = 0; i < 8; ++i) r0[i] = acc[i][j];
    *(float4*)&outp[(size_t)e * HDIM + (td << 3)]     = *(float4*)&r0[0];
    *(float4*)&outp[(size_t)e * HDIM + (td << 3) + 4] = *(float4*)&r0[4];
  }
  if (te == 0) {
    float* kso = ksp + ((size_t)(chunk * 64 + bh) << 7) + (td << 3);
    #pragma unroll
    for (int i = 0; i < 8; ++i) kso[i] = ks[i];
  }
}

__global__ __launch_bounds__(256) void kv_reduce(
    const float* __restrict__ kvp, float* __restrict__ kvT)
{
  int i = blockIdx.x * 256 + threadIdx.x;
  float s = 0.f;
  #pragma unroll
  for (int c = 0; c < 16; ++c) s += kvp[(size_t)c * (64 * 16384) + i];
  kvT[i] = s;
}

// attn[s,e] = (qp[s,:] . kvT[e,:]) / (z[s]+eps); qp = q cols of qkv, out -> v cols.
__global__ __launch_bounds__(256) void attn_ker(
    const unsigned short* __restrict__ qp, const float* __restrict__ kvT,
    const float* __restrict__ ksp, unsigned short* __restrict__ attn)
{
  const int bh = blockIdx.x >> 5, stile = blockIdx.x & 31;
  const int b = bh >> 4, h = bh & 15;
  const int tid = threadIdx.x;
  const int lane = tid & 63, w = tid >> 6;
  const int l15 = lane & 15, l4 = lane >> 4;

  __shared__ unsigned short Qs[128][136];
  __shared__ unsigned short Ks[128][136];
  __shared__ float ksl[128];
  __shared__ float zs[128];

  const size_t qbase = ((size_t)b * NS + (size_t)stile * 128) * QSTR + (size_t)h * HDIM;

  #pragma unroll
  for (int i = 0; i < 8; ++i) {
    int idx = tid + (i << 8);
    int row = idx >> 4, q = idx & 15;
    u16x8 v8 = *(const u16x8*)(qp + qbase + (size_t)row * QSTR + (q << 3));
    *(u16x8*)&Qs[row][q << 3] = v8;
  }
  const float* kvb = kvT + ((size_t)bh << 14);
  #pragma unroll
  for (int i = 0; i < 16; ++i) {
    int idx = tid + (i << 8);
    int row = idx >> 5, q = idx & 31;
    float4 v4 = *(const float4*)(kvb + (size_t)row * HDIM + (q << 2));
    ushort4 w4; w4.x = f2b(v4.x); w4.y = f2b(v4.y); w4.z = f2b(v4.z); w4.w = f2b(v4.w);
    *(ushort4*)&Ks[row][q << 2] = w4;
  }
  if (tid < 128) {
    float s = 0.f;
    #pragma unroll
    for (int c = 0; c < 16; ++c) s += ksp[((size_t)(c * 64 + bh) << 7) + tid];
    ksl[tid] = s;
  }
  __syncthreads();
  if (tid < 128) {
    float z = 0.f;
    #pragma unroll
    for (int dq = 0; dq < 16; ++dq) {
      u16x8 qv = *(const u16x8*)&Qs[tid][dq << 3];
      #pragma unroll
      for (int j = 0; j < 8; ++j) z += b2f(qv[j]) * ksl[(dq << 3) + j];
    }
    zs[tid] = 1.f / (z + EPSV);
  }
  __syncthreads();

  f32x4 acc[2][8] = {};
  #pragma unroll
  for (int kk = 0; kk < 4; ++kk) {
    s16x8 a[2], bb[8];
    #pragma unroll
    for (int mf = 0; mf < 2; ++mf)
      a[mf] = *(const s16x8*)&Qs[(w << 5) + (mf << 4) + l15][(kk << 5) + (l4 << 3)];
    #pragma unroll
    for (int nf = 0; nf < 8; ++nf)
      bb[nf] = *(const s16x8*)&Ks[(nf << 4) + l15][(kk << 5) + (l4 << 3)];
    #pragma unroll
    for (int mf = 0; mf < 2; ++mf)
      #pragma unroll
      for (int nf = 0; nf < 8; ++nf)
        acc[mf][nf] = __builtin_amdgcn_mfma_f32_16x16x32_bf16(a[mf], bb[nf], acc[mf][nf], 0, 0, 0);
  }

  #pragma unroll
  for (int mf = 0; mf < 2; ++mf) {
    #pragma unroll
    for (int r = 0; r < 4; ++r) {
      const int rl = (w << 5) + (mf << 4) + (l4 << 2) + r;
      const float zi = zs[rl];
      #pragma unroll
      for (int nf = 0; nf < 8; ++nf) {
        const int e = (nf << 4) + l15;
        attn[qbase + (size_t)rl * QSTR + e] = f2b(acc[mf][nf][r] * zi);
      }
    }
  }
}

extern "C" void kernel_launch(void* const* d_in, const int* in_sizes, int n_in,
                              void* d_out, int out_size, void* d_ws, size_t ws_size,
                              hipStream_t stream) {
  const float* hs = (const float*)d_in[0];
  const float* qw = (const float*)d_in[1];
  const float* qb = (const float*)d_in[2];
  const float* kw = (const float*)d_in[3];
  const float* kb = (const float*)d_in[4];
  const float* vw = (const float*)d_in[5];
  const float* vb = (const float*)d_in[6];
  const float* ow = (const float*)d_in[7];
  const float* ob = (const float*)d_in[8];

  char* w = (char*)d_ws;
  unsigned short* hsb = (unsigned short*)(w);                  // 64 MiB (dead after QKV gemm)
  unsigned short* qwb = (unsigned short*)(w + 67108864);       // 8 MiB each (q/k/v dead after QKV)
  unsigned short* kwb = (unsigned short*)(w + 75497472);
  unsigned short* vwb = (unsigned short*)(w + 83886080);
  unsigned short* owb = (unsigned short*)(w + 92274688);
  unsigned short* qkv = (unsigned short*)(w + 100663296);      // 192 MiB, row stride 6144
  // aliases over dead regions after QKV:
  float* kvp = (float*)(w);                                    // 64 MiB (16 chunks) over hsb
  float* ksp = (float*)(w + 67108864);                         // 512 KiB over qwb
  float* kvT = (float*)(w + 67108864 + 524288);                // 4 MiB over qwb

  convert_all<<<dim3(24576), dim3(256), 0, stream>>>(hs, qw, kw, vw, ow, hsb, qwb, kwb, vwb, owb);
  // QKV fused: M=16384, N=6144 (q|k|v columns), elu+1 on q,k
  gemm256<1, 1><<<dim3(24 * 64), dim3(512), 0, stream>>>(
      hsb, qwb, kwb, vwb, qb, kb, vb, qkv, 24, HIDC, QSTR);
  kv_partial<<<dim3(1024), dim3(256), 0, stream>>>(qkv + 2048, qkv + 4096, kvp, ksp);
  kv_reduce<<<dim3(4096), dim3(256), 0, stream>>>(kvp, kvT);
  attn_ker<<<dim3(2048), dim3(256), 0, stream>>>(qkv, kvT, ksp, qkv + 4096);
  // final: out = attn @ o_w^T + o_b, A = v-columns of qkv (astr=QSTR), fp32 out
  gemm256<0, 0><<<dim3(8 * 64), dim3(512), 0, stream>>>(
      qkv + 4096, owb, owb, owb, ob, ob, ob, d_out, 8, QSTR, HIDC);
}